// Round 1
// baseline (6916.003 us; speedup 1.0000x reference)
//
#include <hip/hip_runtime.h>
#include <cstddef>

#define D_MODEL 1024
#define D_INNER 2048
#define DT_RANK 64
#define D_STATE 8
#define NLAYERS 4
#define BATCH 2
#define SEQ 1024
#define M_ROWS (BATCH*SEQ)   /* 2048 */
#define VOCAB 32000

__device__ __forceinline__ float sigmoidf_(float x) { return 1.f / (1.f + __expf(-x)); }

// ---------------------------------------------------------------------------
// Embedding gather: x[m,:] = embed[ids[m],:]   (one block per row, 256 thr)
// ---------------------------------------------------------------------------
__global__ __launch_bounds__(256) void gather_kernel(const int* __restrict__ ids,
                                                     const float* __restrict__ embed,
                                                     float* __restrict__ x)
{
    int m = blockIdx.x;
    int t = threadIdx.x;
    int id = ids[m];
    float4 v = ((const float4*)(embed + (size_t)id * D_MODEL))[t];
    ((float4*)(x + (size_t)m * D_MODEL))[t] = v;
}

// ---------------------------------------------------------------------------
// GEMM  C[M,N] = A[M,K] * B[N,K]^T   (both row-major, K contiguous; NT)
// 64x64 tile, BK=16, 256 threads, 4x4 micro-tile per thread.
// EPI: 0 none, 1 bias+softplus (per col), 2 bias (per col)
// Requires K % 16 == 0 (true here: 1024, 2048, 64).
// ---------------------------------------------------------------------------
template<int EPI>
__global__ __launch_bounds__(256) void gemm_nt(const float* __restrict__ A, int lda,
                                               const float* __restrict__ B, int ldb,
                                               float* __restrict__ C, int ldc,
                                               int M, int N, int K,
                                               const float* __restrict__ bias)
{
    __shared__ float As[16][68];
    __shared__ float Bs[16][68];
    const int bm = blockIdx.y * 64, bn = blockIdx.x * 64;
    const int tid = threadIdx.x;
    const int tx = tid & 15, ty = tid >> 4;
    const int lr = tid >> 2;          // 0..63 tile row
    const int lk = (tid & 3) << 2;    // 0,4,8,12 k offset

    float acc[4][4] = {};

    for (int k0 = 0; k0 < K; k0 += 16) {
        float4 av = make_float4(0.f, 0.f, 0.f, 0.f);
        float4 bv = make_float4(0.f, 0.f, 0.f, 0.f);
        int arow = bm + lr;
        if (arow < M) av = *(const float4*)(A + (size_t)arow * lda + k0 + lk);
        int brow = bn + lr;
        if (brow < N) bv = *(const float4*)(B + (size_t)brow * ldb + k0 + lk);
        As[lk + 0][lr] = av.x; As[lk + 1][lr] = av.y; As[lk + 2][lr] = av.z; As[lk + 3][lr] = av.w;
        Bs[lk + 0][lr] = bv.x; Bs[lk + 1][lr] = bv.y; Bs[lk + 2][lr] = bv.z; Bs[lk + 3][lr] = bv.w;
        __syncthreads();
        #pragma unroll
        for (int kk = 0; kk < 16; ++kk) {
            float a0 = As[kk][ty * 4 + 0], a1 = As[kk][ty * 4 + 1];
            float a2 = As[kk][ty * 4 + 2], a3 = As[kk][ty * 4 + 3];
            float b0 = Bs[kk][tx * 4 + 0], b1 = Bs[kk][tx * 4 + 1];
            float b2 = Bs[kk][tx * 4 + 2], b3 = Bs[kk][tx * 4 + 3];
            acc[0][0] += a0 * b0; acc[0][1] += a0 * b1; acc[0][2] += a0 * b2; acc[0][3] += a0 * b3;
            acc[1][0] += a1 * b0; acc[1][1] += a1 * b1; acc[1][2] += a1 * b2; acc[1][3] += a1 * b3;
            acc[2][0] += a2 * b0; acc[2][1] += a2 * b1; acc[2][2] += a2 * b2; acc[2][3] += a2 * b3;
            acc[3][0] += a3 * b0; acc[3][1] += a3 * b1; acc[3][2] += a3 * b2; acc[3][3] += a3 * b3;
        }
        __syncthreads();
    }

    #pragma unroll
    for (int i = 0; i < 4; ++i) {
        int row = bm + ty * 4 + i;
        if (row >= M) continue;
        #pragma unroll
        for (int j = 0; j < 4; ++j) {
            int col = bn + tx * 4 + j;
            if (col >= N) continue;
            float v = acc[i][j];
            if (EPI == 1) { v += bias[col]; v = (v > 20.f) ? v : log1pf(__expf(v)); }
            else if (EPI == 2) { v += bias[col]; }
            C[(size_t)row * ldc + col] = v;
        }
    }
}

// ---------------------------------------------------------------------------
// Causal depthwise conv1d (kernel 4) + bias + SiLU.
// xz: (M_ROWS, 2*D_INNER); xc column block = first D_INNER cols.
// out xc: (M_ROWS, D_INNER)
// ---------------------------------------------------------------------------
__global__ __launch_bounds__(256) void conv_silu_kernel(const float* __restrict__ xz,
                                                        const float* __restrict__ cw,
                                                        const float* __restrict__ cb,
                                                        float* __restrict__ xc)
{
    int idx = blockIdx.x * 256 + threadIdx.x;      // over M_ROWS*D_INNER
    int d = idx & (D_INNER - 1);
    int m = idx >> 11;                              // /2048
    int l = m & (SEQ - 1);
    int b = m >> 10;
    float w0 = cw[d * 4 + 0], w1 = cw[d * 4 + 1], w2 = cw[d * 4 + 2], w3 = cw[d * 4 + 3];
    float s = cb[d];
    const float* base = xz + ((size_t)b * SEQ) * (2 * D_INNER) + d;
    if (l - 3 >= 0) s += base[(size_t)(l - 3) * (2 * D_INNER)] * w0;
    if (l - 2 >= 0) s += base[(size_t)(l - 2) * (2 * D_INNER)] * w1;
    if (l - 1 >= 0) s += base[(size_t)(l - 1) * (2 * D_INNER)] * w2;
    s += base[(size_t)l * (2 * D_INNER)] * w3;
    xc[(size_t)m * D_INNER + d] = s * sigmoidf_(s);
}

// ---------------------------------------------------------------------------
// Selective scan, fused with D-skip and SiLU(z) gating.
// 8 lanes per (b,d) channel, one lane per state n. y written in-place over dt.
// ---------------------------------------------------------------------------
__global__ __launch_bounds__(256) void scan_kernel(const float* __restrict__ dt,
                                                   const float* __restrict__ xdbl,
                                                   const float* __restrict__ xc,
                                                   const float* __restrict__ xz,
                                                   const float* __restrict__ A_log,
                                                   const float* __restrict__ Dp,
                                                   float* __restrict__ y)
{
    int t = blockIdx.x * 256 + threadIdx.x;
    int n = t & 7;
    int ch = t >> 3;                 // 0..4095
    int d = ch & (D_INNER - 1);
    int b = ch >> 11;

    float A = -__expf(A_log[d * D_STATE + n]);
    float Dv = Dp[d];

    const float* dtp = dt + (size_t)b * SEQ * D_INNER + d;
    const float* xcp = xc + (size_t)b * SEQ * D_INNER + d;
    const float* zp  = xz + (size_t)b * SEQ * (2 * D_INNER) + D_INNER + d;
    const float* Bp  = xdbl + (size_t)b * SEQ * 80 + DT_RANK + n;
    const float* Cp  = xdbl + (size_t)b * SEQ * 80 + DT_RANK + D_STATE + n;
    float* yp = y + (size_t)b * SEQ * D_INNER + d;

    float h = 0.f;
    for (int l = 0; l < SEQ; ++l) {
        float dtv = dtp[(size_t)l * D_INNER];
        float xcv = xcp[(size_t)l * D_INNER];
        float Bv = Bp[(size_t)l * 80];
        float Cv = Cp[(size_t)l * 80];
        float dA = __expf(dtv * A);
        h = dA * h + dtv * Bv * xcv;
        float part = h * Cv;
        part += __shfl_xor(part, 1);
        part += __shfl_xor(part, 2);
        part += __shfl_xor(part, 4);
        if (n == 0) {
            float zv = zp[(size_t)l * (2 * D_INNER)];
            yp[(size_t)l * D_INNER] = (part + xcv * Dv) * (zv * sigmoidf_(zv));
        }
    }
}

// ---------------------------------------------------------------------------
// LayerNorm over last dim (1024). One block (256 thr) per row.
// ADD=true: out = LN(extra + xin); ADD=false: out = LN(xin).
// Safe for out == xin (block-local row).
// ---------------------------------------------------------------------------
template<bool ADD>
__global__ __launch_bounds__(256) void ln_kernel(const float* __restrict__ extra,
                                                 const float* __restrict__ xin,
                                                 float* __restrict__ xout,
                                                 const float* __restrict__ g,
                                                 const float* __restrict__ bb)
{
    int m = blockIdx.x;
    int t = threadIdx.x;
    float4 v = ((const float4*)(xin + (size_t)m * D_MODEL))[t];
    if (ADD) {
        float4 e = ((const float4*)(extra + (size_t)m * D_MODEL))[t];
        v.x += e.x; v.y += e.y; v.z += e.z; v.w += e.w;
    }
    float s  = v.x + v.y + v.z + v.w;
    float s2 = v.x * v.x + v.y * v.y + v.z * v.z + v.w * v.w;
    for (int off = 32; off; off >>= 1) {
        s  += __shfl_down(s, off);
        s2 += __shfl_down(s2, off);
    }
    __shared__ float red[8];
    int wid = t >> 6, lane = t & 63;
    if (lane == 0) { red[wid] = s; red[wid + 4] = s2; }
    __syncthreads();
    if (t == 0) {
        float a  = red[0] + red[1] + red[2] + red[3];
        float b2 = red[4] + red[5] + red[6] + red[7];
        float mu = a * (1.f / D_MODEL);
        red[0] = mu;
        red[4] = b2 * (1.f / D_MODEL) - mu * mu;
    }
    __syncthreads();
    float mu = red[0];
    float rs = rsqrtf(red[4] + 1e-5f);
    float4 gg = ((const float4*)g)[t];
    float4 bv = ((const float4*)bb)[t];
    float4 o;
    o.x = (v.x - mu) * rs * gg.x + bv.x;
    o.y = (v.y - mu) * rs * gg.y + bv.y;
    o.z = (v.z - mu) * rs * gg.z + bv.z;
    o.w = (v.w - mu) * rs * gg.w + bv.w;
    ((float4*)(xout + (size_t)m * D_MODEL))[t] = o;
}

// ---------------------------------------------------------------------------
extern "C" void kernel_launch(void* const* d_in, const int* in_sizes, int n_in,
                              void* d_out, int out_size, void* d_ws, size_t ws_size,
                              hipStream_t stream)
{
    const int*   ids      = (const int*)d_in[0];
    const float* embed    = (const float*)d_in[1];
    const float* in_proj  = (const float*)d_in[2];
    const float* conv_w   = (const float*)d_in[3];
    const float* conv_b   = (const float*)d_in[4];
    const float* x_proj   = (const float*)d_in[5];
    const float* dt_w     = (const float*)d_in[6];
    const float* dt_b     = (const float*)d_in[7];
    const float* A_log    = (const float*)d_in[8];
    const float* Dp       = (const float*)d_in[9];
    const float* out_proj = (const float*)d_in[10];
    const float* ln_g     = (const float*)d_in[11];
    const float* ln_b     = (const float*)d_in[12];
    const float* fn_g     = (const float*)d_in[13];
    const float* fn_b     = (const float*)d_in[14];
    const float* fc_w     = (const float*)d_in[15];
    const float* fc_b     = (const float*)d_in[16];
    float* logits = (float*)d_out;

    // workspace layout (floats)
    float* ws = (float*)d_ws;
    float* x     = ws;                                   // 2048*1024
    float* xz    = x + (size_t)M_ROWS * D_MODEL;         // 2048*4096
    float* xc    = xz + (size_t)M_ROWS * 2 * D_INNER;    // 2048*2048
    float* xdbl  = xc + (size_t)M_ROWS * D_INNER;        // 2048*80
    float* dtbuf = xdbl + (size_t)M_ROWS * 80;           // 2048*2048 (y aliases)
    float* tmp   = dtbuf + (size_t)M_ROWS * D_INNER;     // 2048*1024 (xf aliases)

    // 1. embedding
    gather_kernel<<<M_ROWS, 256, 0, stream>>>(ids, embed, x);

    for (int i = 0; i < NLAYERS; ++i) {
        const float* W_in  = in_proj + (size_t)i * (2 * D_INNER) * D_MODEL;
        const float* cw    = conv_w + (size_t)i * D_INNER * 4;
        const float* cb    = conv_b + (size_t)i * D_INNER;
        const float* W_x   = x_proj + (size_t)i * 80 * D_INNER;
        const float* W_dt  = dt_w + (size_t)i * D_INNER * DT_RANK;
        const float* b_dt  = dt_b + (size_t)i * D_INNER;
        const float* Al    = A_log + (size_t)i * D_INNER * D_STATE;
        const float* Dl    = Dp + (size_t)i * D_INNER;
        const float* W_out = out_proj + (size_t)i * D_MODEL * D_INNER;
        const float* g     = ln_g + (size_t)i * D_MODEL;
        const float* bb    = ln_b + (size_t)i * D_MODEL;

        // xz = x @ in_proj^T        (2048 x 4096, K=1024)
        gemm_nt<0><<<dim3(4096 / 64, M_ROWS / 64), 256, 0, stream>>>(
            x, D_MODEL, W_in, D_MODEL, xz, 2 * D_INNER, M_ROWS, 2 * D_INNER, D_MODEL, nullptr);

        // xc = silu(causal depthwise conv(xz[:, :2048]) + cb)
        conv_silu_kernel<<<(M_ROWS * D_INNER) / 256, 256, 0, stream>>>(xz, cw, cb, xc);

        // x_dbl = xc @ x_proj^T     (2048 x 80, K=2048)
        gemm_nt<0><<<dim3((80 + 63) / 64, M_ROWS / 64), 256, 0, stream>>>(
            xc, D_INNER, W_x, D_INNER, xdbl, 80, M_ROWS, 80, D_INNER, nullptr);

        // dt = softplus(x_dbl[:, :64] @ dt_w^T + b_dt)   (2048 x 2048, K=64)
        gemm_nt<1><<<dim3(D_INNER / 64, M_ROWS / 64), 256, 0, stream>>>(
            xdbl, 80, W_dt, DT_RANK, dtbuf, D_INNER, M_ROWS, D_INNER, DT_RANK, b_dt);

        // selective scan (y in-place over dtbuf)
        scan_kernel<<<(BATCH * D_INNER * 8) / 256, 256, 0, stream>>>(
            dtbuf, xdbl, xc, xz, Al, Dl, dtbuf);

        // tmp = y @ out_proj^T      (2048 x 1024, K=2048)
        gemm_nt<0><<<dim3(D_MODEL / 64, M_ROWS / 64), 256, 0, stream>>>(
            dtbuf, D_INNER, W_out, D_INNER, tmp, D_MODEL, M_ROWS, D_MODEL, D_INNER, nullptr);

        // x = LN(tmp + x)
        ln_kernel<true><<<M_ROWS, 256, 0, stream>>>(tmp, x, x, g, bb);
    }

    // final LN (into tmp)
    ln_kernel<false><<<M_ROWS, 256, 0, stream>>>(nullptr, x, tmp, fn_g, fn_b);

    // logits = xf @ fc_w^T + fc_b   (2048 x 32000, K=1024)
    gemm_nt<2><<<dim3(VOCAB / 64, M_ROWS / 64), 256, 0, stream>>>(
        tmp, D_MODEL, fc_w, D_MODEL, logits, VOCAB, M_ROWS, VOCAB, D_MODEL, fc_b);
}

// Round 2
// 2267.532 us; speedup vs baseline: 3.0500x; 3.0500x over previous
//
#include <hip/hip_runtime.h>
#include <cstddef>
#include <cstdint>

#define D_MODEL 1024
#define D_INNER 2048
#define DT_RANK 64
#define D_STATE 8
#define NLAYERS 4
#define BATCH 2
#define SEQ 1024
#define M_ROWS (BATCH*SEQ)   /* 2048 */
#define VOCAB 32000

typedef __attribute__((ext_vector_type(8))) short short8;
typedef __attribute__((ext_vector_type(4))) float f32x4;

__device__ __forceinline__ float sigmoidf_(float x) { return 1.f / (1.f + __expf(-x)); }

__device__ __forceinline__ unsigned short f2bf(float f) {
    unsigned u = __float_as_uint(f);
    u += 0x7fffu + ((u >> 16) & 1u);         // round-to-nearest-even
    return (unsigned short)(u >> 16);
}

// ---------------------------------------------------------------------------
// fp32 -> bf16 cast, 4 elems/thread. n4 = n/4 (all sizes divisible by 4).
// ---------------------------------------------------------------------------
__global__ __launch_bounds__(256) void cast_kernel(const float* __restrict__ in,
                                                   unsigned short* __restrict__ out, int n4)
{
    int i = blockIdx.x * 256 + threadIdx.x;
    if (i >= n4) return;
    float4 v = ((const float4*)in)[i];
    ushort4 o;
    o.x = f2bf(v.x); o.y = f2bf(v.y); o.z = f2bf(v.z); o.w = f2bf(v.w);
    ((ushort4*)out)[i] = o;
}

// ---------------------------------------------------------------------------
// Embedding gather
// ---------------------------------------------------------------------------
__global__ __launch_bounds__(256) void gather_kernel(const int* __restrict__ ids,
                                                     const float* __restrict__ embed,
                                                     float* __restrict__ x)
{
    int m = blockIdx.x;
    int t = threadIdx.x;
    int id = ids[m];
    float4 v = ((const float4*)(embed + (size_t)id * D_MODEL))[t];
    ((float4*)(x + (size_t)m * D_MODEL))[t] = v;
}

// ---------------------------------------------------------------------------
// bf16 MFMA GEMM  C[M,N] = A[M,K] * B[N,K]^T  (fp32 out)
// 128x128 tile, BK=32, 256 thr = 4 waves, each wave 64x64 (4x4 frags 16x16x32).
// Requires M%128==0, N%128==0, K%32==0.  EPI: 0 none, 2 +bias[col].
// ---------------------------------------------------------------------------
template<int EPI>
__global__ __launch_bounds__(256) void gemm_bf16_nt(const unsigned short* __restrict__ A, int lda,
                                                    const unsigned short* __restrict__ B, int ldb,
                                                    float* __restrict__ C, int ldc,
                                                    int K, const float* __restrict__ bias)
{
    __shared__ unsigned short As[128 * 32];
    __shared__ unsigned short Bs[128 * 32];
    const int tid = threadIdx.x;
    const int bm = blockIdx.y * 128, bn = blockIdx.x * 128;
    const int wid = tid >> 6, lane = tid & 63;
    const int wm = (wid >> 1) * 64, wn = (wid & 1) * 64;
    const int lrow = lane & 15, lkg = lane >> 4;

    // staging: thread t covers LDS bytes [t*16, t*16+16) => row t/4, k-seg t%4
    const int srow = tid >> 2;
    const int skg = tid & 3;
    const unsigned short* Ag = A + (size_t)(bm + srow) * lda + skg * 8;
    const unsigned short* Bg = B + (size_t)(bn + srow) * ldb + skg * 8;
    unsigned short* Al = As + tid * 8;
    unsigned short* Bl = Bs + tid * 8;
    const size_t a64 = (size_t)64 * lda;
    const size_t b64 = (size_t)64 * ldb;

    f32x4 acc[4][4];
    #pragma unroll
    for (int i = 0; i < 4; ++i)
        #pragma unroll
        for (int j = 0; j < 4; ++j)
            acc[i][j] = f32x4{0.f, 0.f, 0.f, 0.f};

    for (int k0 = 0; k0 < K; k0 += 32) {
        __builtin_amdgcn_global_load_lds((const __attribute__((address_space(1))) void*)(Ag + k0),
                                         (__attribute__((address_space(3))) void*)Al, 16, 0, 0);
        __builtin_amdgcn_global_load_lds((const __attribute__((address_space(1))) void*)(Ag + a64 + k0),
                                         (__attribute__((address_space(3))) void*)(Al + 2048), 16, 0, 0);
        __builtin_amdgcn_global_load_lds((const __attribute__((address_space(1))) void*)(Bg + k0),
                                         (__attribute__((address_space(3))) void*)Bl, 16, 0, 0);
        __builtin_amdgcn_global_load_lds((const __attribute__((address_space(1))) void*)(Bg + b64 + k0),
                                         (__attribute__((address_space(3))) void*)(Bl + 2048), 16, 0, 0);
        __syncthreads();   // compiler drains vmcnt before barrier -> tiles ready

        short8 af[4], bf[4];
        #pragma unroll
        for (int i = 0; i < 4; ++i)
            af[i] = *(const short8*)(As + (wm + 16 * i + lrow) * 32 + lkg * 8);
        #pragma unroll
        for (int j = 0; j < 4; ++j)
            bf[j] = *(const short8*)(Bs + (wn + 16 * j + lrow) * 32 + lkg * 8);
        #pragma unroll
        for (int i = 0; i < 4; ++i)
            #pragma unroll
            for (int j = 0; j < 4; ++j)
                acc[i][j] = __builtin_amdgcn_mfma_f32_16x16x32_bf16(af[i], bf[j], acc[i][j], 0, 0, 0);
        __syncthreads();   // all waves done with LDS before next stage
    }

    // C/D layout: col = lane&15, row = 4*(lane>>4)+r
    const int crow = bm + wm + lkg * 4;
    const int ccol = bn + wn + lrow;
    #pragma unroll
    for (int i = 0; i < 4; ++i) {
        #pragma unroll
        for (int j = 0; j < 4; ++j) {
            float bv = (EPI == 2) ? bias[ccol + 16 * j] : 0.f;
            float* Cp = C + (size_t)(crow + 16 * i) * ldc + ccol + 16 * j;
            #pragma unroll
            for (int r = 0; r < 4; ++r)
                Cp[(size_t)r * ldc] = acc[i][j][r] + bv;
        }
    }
}

// ---------------------------------------------------------------------------
// fp32 GEMM (kept for the small/odd shapes: x_proj N=80, dt K=64)
// EPI: 0 none, 1 bias+softplus
// ---------------------------------------------------------------------------
template<int EPI>
__global__ __launch_bounds__(256) void gemm_nt(const float* __restrict__ A, int lda,
                                               const float* __restrict__ B, int ldb,
                                               float* __restrict__ C, int ldc,
                                               int M, int N, int K,
                                               const float* __restrict__ bias)
{
    __shared__ float As[16][68];
    __shared__ float Bs[16][68];
    const int bm = blockIdx.y * 64, bn = blockIdx.x * 64;
    const int tid = threadIdx.x;
    const int tx = tid & 15, ty = tid >> 4;
    const int lr = tid >> 2;
    const int lk = (tid & 3) << 2;

    float acc[4][4] = {};

    for (int k0 = 0; k0 < K; k0 += 16) {
        float4 av = make_float4(0.f, 0.f, 0.f, 0.f);
        float4 bv = make_float4(0.f, 0.f, 0.f, 0.f);
        int arow = bm + lr;
        if (arow < M) av = *(const float4*)(A + (size_t)arow * lda + k0 + lk);
        int brow = bn + lr;
        if (brow < N) bv = *(const float4*)(B + (size_t)brow * ldb + k0 + lk);
        As[lk + 0][lr] = av.x; As[lk + 1][lr] = av.y; As[lk + 2][lr] = av.z; As[lk + 3][lr] = av.w;
        Bs[lk + 0][lr] = bv.x; Bs[lk + 1][lr] = bv.y; Bs[lk + 2][lr] = bv.z; Bs[lk + 3][lr] = bv.w;
        __syncthreads();
        #pragma unroll
        for (int kk = 0; kk < 16; ++kk) {
            float a0 = As[kk][ty * 4 + 0], a1 = As[kk][ty * 4 + 1];
            float a2 = As[kk][ty * 4 + 2], a3 = As[kk][ty * 4 + 3];
            float b0 = Bs[kk][tx * 4 + 0], b1 = Bs[kk][tx * 4 + 1];
            float b2 = Bs[kk][tx * 4 + 2], b3 = Bs[kk][tx * 4 + 3];
            acc[0][0] += a0 * b0; acc[0][1] += a0 * b1; acc[0][2] += a0 * b2; acc[0][3] += a0 * b3;
            acc[1][0] += a1 * b0; acc[1][1] += a1 * b1; acc[1][2] += a1 * b2; acc[1][3] += a1 * b3;
            acc[2][0] += a2 * b0; acc[2][1] += a2 * b1; acc[2][2] += a2 * b2; acc[2][3] += a2 * b3;
            acc[3][0] += a3 * b0; acc[3][1] += a3 * b1; acc[3][2] += a3 * b2; acc[3][3] += a3 * b3;
        }
        __syncthreads();
    }

    #pragma unroll
    for (int i = 0; i < 4; ++i) {
        int row = bm + ty * 4 + i;
        if (row >= M) continue;
        #pragma unroll
        for (int j = 0; j < 4; ++j) {
            int col = bn + tx * 4 + j;
            if (col >= N) continue;
            float v = acc[i][j];
            if (EPI == 1) { v += bias[col]; v = (v > 20.f) ? v : log1pf(__expf(v)); }
            C[(size_t)row * ldc + col] = v;
        }
    }
}

// ---------------------------------------------------------------------------
// Causal depthwise conv1d (k=4) + bias + SiLU
// ---------------------------------------------------------------------------
__global__ __launch_bounds__(256) void conv_silu_kernel(const float* __restrict__ xz,
                                                        const float* __restrict__ cw,
                                                        const float* __restrict__ cb,
                                                        float* __restrict__ xc)
{
    int idx = blockIdx.x * 256 + threadIdx.x;
    int d = idx & (D_INNER - 1);
    int m = idx >> 11;
    int l = m & (SEQ - 1);
    int b = m >> 10;
    float w0 = cw[d * 4 + 0], w1 = cw[d * 4 + 1], w2 = cw[d * 4 + 2], w3 = cw[d * 4 + 3];
    float s = cb[d];
    const float* base = xz + ((size_t)b * SEQ) * (2 * D_INNER) + d;
    if (l - 3 >= 0) s += base[(size_t)(l - 3) * (2 * D_INNER)] * w0;
    if (l - 2 >= 0) s += base[(size_t)(l - 2) * (2 * D_INNER)] * w1;
    if (l - 1 >= 0) s += base[(size_t)(l - 1) * (2 * D_INNER)] * w2;
    s += base[(size_t)l * (2 * D_INNER)] * w3;
    xc[(size_t)m * D_INNER + d] = s * sigmoidf_(s);
}

// ---------------------------------------------------------------------------
// Selective scan, LDS-tiled. Block = 256 thr = 32 channels x 8 states.
// Grid = BATCH * D_INNER/32 = 128. L tiled in chunks of 64 with coalesced
// staging of dt/xc/z (32-wide) and B/C (8-wide).
// ---------------------------------------------------------------------------
#define SCAN_CH 32
#define SCAN_LT 64
__global__ __launch_bounds__(256) void scan_kernel(const float* __restrict__ dt,
                                                   const float* __restrict__ xdbl,
                                                   const float* __restrict__ xc,
                                                   const float* __restrict__ xz,
                                                   const float* __restrict__ A_log,
                                                   const float* __restrict__ Dp,
                                                   float* __restrict__ y)
{
    __shared__ float dt_s[SCAN_LT][SCAN_CH];
    __shared__ float xc_s[SCAN_LT][SCAN_CH];
    __shared__ float z_s[SCAN_LT][SCAN_CH];
    __shared__ float B_s[SCAN_LT][8];
    __shared__ float C_s[SCAN_LT][8];

    const int b = blockIdx.x & 1;
    const int d0 = (blockIdx.x >> 1) * SCAN_CH;
    const int tid = threadIdx.x;
    const int ch = tid >> 3, n = tid & 7;
    const int d = d0 + ch;

    const float Av = -__expf(A_log[d * D_STATE + n]);
    const float Dv = Dp[d];

    const float* dtb = dt + (size_t)b * SEQ * D_INNER + d0;
    const float* xcb = xc + (size_t)b * SEQ * D_INNER + d0;
    const float* zb  = xz + (size_t)b * SEQ * (2 * D_INNER) + D_INNER + d0;
    const float* xdb = xdbl + (size_t)b * SEQ * 80 + DT_RANK;
    float* yb = y + (size_t)b * SEQ * D_INNER + d;

    float h = 0.f;
    for (int lt = 0; lt < SEQ; lt += SCAN_LT) {
        __syncthreads();
        #pragma unroll
        for (int i = 0; i < (SCAN_LT * SCAN_CH) / 256; ++i) {
            int idx = i * 256 + tid;
            int r = idx >> 5, c = idx & 31;
            size_t g = (size_t)(lt + r) * D_INNER + c;
            dt_s[r][c] = dtb[g];
            xc_s[r][c] = xcb[g];
            z_s[r][c]  = zb[(size_t)(lt + r) * (2 * D_INNER) + c];
        }
        for (int idx = tid; idx < SCAN_LT * 8; idx += 256) {
            int r = idx >> 3, c = idx & 7;
            B_s[r][c] = xdb[(size_t)(lt + r) * 80 + c];
            C_s[r][c] = xdb[(size_t)(lt + r) * 80 + 8 + c];
        }
        __syncthreads();
        for (int l = 0; l < SCAN_LT; ++l) {
            float dtv = dt_s[l][ch];
            float xcv = xc_s[l][ch];
            float Bv = B_s[l][n], Cv = C_s[l][n];
            h = __expf(dtv * Av) * h + dtv * Bv * xcv;
            float part = h * Cv;
            part += __shfl_xor(part, 1);
            part += __shfl_xor(part, 2);
            part += __shfl_xor(part, 4);
            if (n == 0) {
                float zv = z_s[l][ch];
                yb[(size_t)(lt + l) * D_INNER] = (part + xcv * Dv) * (zv * sigmoidf_(zv));
            }
        }
    }
}

// ---------------------------------------------------------------------------
// LayerNorm (1024). ADD: out = LN(extra + xin) else LN(xin).
// ---------------------------------------------------------------------------
template<bool ADD>
__global__ __launch_bounds__(256) void ln_kernel(const float* __restrict__ extra,
                                                 const float* __restrict__ xin,
                                                 float* __restrict__ xout,
                                                 const float* __restrict__ g,
                                                 const float* __restrict__ bb)
{
    int m = blockIdx.x;
    int t = threadIdx.x;
    float4 v = ((const float4*)(xin + (size_t)m * D_MODEL))[t];
    if (ADD) {
        float4 e = ((const float4*)(extra + (size_t)m * D_MODEL))[t];
        v.x += e.x; v.y += e.y; v.z += e.z; v.w += e.w;
    }
    float s  = v.x + v.y + v.z + v.w;
    float s2 = v.x * v.x + v.y * v.y + v.z * v.z + v.w * v.w;
    for (int off = 32; off; off >>= 1) {
        s  += __shfl_down(s, off);
        s2 += __shfl_down(s2, off);
    }
    __shared__ float red[8];
    int wid = t >> 6, lane = t & 63;
    if (lane == 0) { red[wid] = s; red[wid + 4] = s2; }
    __syncthreads();
    if (t == 0) {
        float a  = red[0] + red[1] + red[2] + red[3];
        float b2 = red[4] + red[5] + red[6] + red[7];
        float mu = a * (1.f / D_MODEL);
        red[0] = mu;
        red[4] = b2 * (1.f / D_MODEL) - mu * mu;
    }
    __syncthreads();
    float mu = red[0];
    float rs = rsqrtf(red[4] + 1e-5f);
    float4 gg = ((const float4*)g)[t];
    float4 bv = ((const float4*)bb)[t];
    float4 o;
    o.x = (v.x - mu) * rs * gg.x + bv.x;
    o.y = (v.y - mu) * rs * gg.y + bv.y;
    o.z = (v.z - mu) * rs * gg.z + bv.z;
    o.w = (v.w - mu) * rs * gg.w + bv.w;
    ((float4*)(xout + (size_t)m * D_MODEL))[t] = o;
}

// ---------------------------------------------------------------------------
extern "C" void kernel_launch(void* const* d_in, const int* in_sizes, int n_in,
                              void* d_out, int out_size, void* d_ws, size_t ws_size,
                              hipStream_t stream)
{
    const int*   ids      = (const int*)d_in[0];
    const float* embed    = (const float*)d_in[1];
    const float* in_proj  = (const float*)d_in[2];
    const float* conv_w   = (const float*)d_in[3];
    const float* conv_b   = (const float*)d_in[4];
    const float* x_proj   = (const float*)d_in[5];
    const float* dt_w     = (const float*)d_in[6];
    const float* dt_b     = (const float*)d_in[7];
    const float* A_log    = (const float*)d_in[8];
    const float* Dp       = (const float*)d_in[9];
    const float* out_proj = (const float*)d_in[10];
    const float* ln_g     = (const float*)d_in[11];
    const float* ln_b     = (const float*)d_in[12];
    const float* fn_g     = (const float*)d_in[13];
    const float* fn_b     = (const float*)d_in[14];
    const float* fc_w     = (const float*)d_in[15];
    const float* fc_b     = (const float*)d_in[16];
    float* logits = (float*)d_out;

    // ---- workspace layout ----
    float* ws = (float*)d_ws;
    float* x     = ws;                                   // 2048*1024
    float* xz    = x + (size_t)M_ROWS * D_MODEL;         // 2048*4096
    float* xc    = xz + (size_t)M_ROWS * 2 * D_INNER;    // 2048*2048
    float* xdbl  = xc + (size_t)M_ROWS * D_INNER;        // 2048*80
    float* dtbuf = xdbl + (size_t)M_ROWS * 80;           // 2048*2048 (y aliases)
    float* tmp   = dtbuf + (size_t)M_ROWS * D_INNER;     // 2048*1024

    unsigned short* xb    = (unsigned short*)(tmp + (size_t)M_ROWS * D_MODEL);
    unsigned short* yb    = xb + (size_t)M_ROWS * D_MODEL;
    unsigned short* wb_in = yb + (size_t)M_ROWS * D_INNER;
    unsigned short* wb_out= wb_in + (size_t)NLAYERS * 2 * D_INNER * D_MODEL;
    unsigned short* wb_fc = wb_out + (size_t)NLAYERS * D_MODEL * D_INNER;

    // ---- weight casts (per call; deterministic) ----
    {
        int n4 = NLAYERS * 2 * D_INNER * D_MODEL / 4;
        cast_kernel<<<(n4 + 255) / 256, 256, 0, stream>>>(in_proj, wb_in, n4);
        n4 = NLAYERS * D_MODEL * D_INNER / 4;
        cast_kernel<<<(n4 + 255) / 256, 256, 0, stream>>>(out_proj, wb_out, n4);
        n4 = VOCAB * D_MODEL / 4;
        cast_kernel<<<(n4 + 255) / 256, 256, 0, stream>>>(fc_w, wb_fc, n4);
    }

    // ---- embedding ----
    gather_kernel<<<M_ROWS, 256, 0, stream>>>(ids, embed, x);

    for (int i = 0; i < NLAYERS; ++i) {
        const unsigned short* W_in_b  = wb_in + (size_t)i * 2 * D_INNER * D_MODEL;
        const unsigned short* W_out_b = wb_out + (size_t)i * D_MODEL * D_INNER;
        const float* cw    = conv_w + (size_t)i * D_INNER * 4;
        const float* cb    = conv_b + (size_t)i * D_INNER;
        const float* W_x   = x_proj + (size_t)i * 80 * D_INNER;
        const float* W_dt  = dt_w + (size_t)i * D_INNER * DT_RANK;
        const float* b_dt  = dt_b + (size_t)i * D_INNER;
        const float* Al    = A_log + (size_t)i * D_INNER * D_STATE;
        const float* Dl    = Dp + (size_t)i * D_INNER;
        const float* g     = ln_g + (size_t)i * D_MODEL;
        const float* bb    = ln_b + (size_t)i * D_MODEL;

        // cast x -> bf16
        int n4 = M_ROWS * D_MODEL / 4;
        cast_kernel<<<(n4 + 255) / 256, 256, 0, stream>>>(x, xb, n4);

        // xz = x @ in_proj^T   (2048 x 4096, K=1024)  [bf16 MFMA]
        gemm_bf16_nt<0><<<dim3(2 * D_INNER / 128, M_ROWS / 128), 256, 0, stream>>>(
            xb, D_MODEL, W_in_b, D_MODEL, xz, 2 * D_INNER, D_MODEL, nullptr);

        // xc = silu(conv(xz[:, :2048]) + cb)
        conv_silu_kernel<<<(M_ROWS * D_INNER) / 256, 256, 0, stream>>>(xz, cw, cb, xc);

        // x_dbl = xc @ x_proj^T   (2048 x 80, K=2048)  [fp32]
        gemm_nt<0><<<dim3((80 + 63) / 64, M_ROWS / 64), 256, 0, stream>>>(
            xc, D_INNER, W_x, D_INNER, xdbl, 80, M_ROWS, 80, D_INNER, nullptr);

        // dt = softplus(x_dbl[:, :64] @ dt_w^T + b_dt)  [fp32]
        gemm_nt<1><<<dim3(D_INNER / 64, M_ROWS / 64), 256, 0, stream>>>(
            xdbl, 80, W_dt, DT_RANK, dtbuf, D_INNER, M_ROWS, D_INNER, DT_RANK, b_dt);

        // selective scan (y in-place over dtbuf)
        scan_kernel<<<BATCH * (D_INNER / SCAN_CH), 256, 0, stream>>>(
            dtbuf, xdbl, xc, xz, Al, Dl, dtbuf);

        // cast y -> bf16
        n4 = M_ROWS * D_INNER / 4;
        cast_kernel<<<(n4 + 255) / 256, 256, 0, stream>>>(dtbuf, yb, n4);

        // tmp = y @ out_proj^T   (2048 x 1024, K=2048)  [bf16 MFMA]
        gemm_bf16_nt<0><<<dim3(D_MODEL / 128, M_ROWS / 128), 256, 0, stream>>>(
            yb, D_INNER, W_out_b, D_INNER, tmp, D_MODEL, D_INNER, nullptr);

        // x = LN(tmp + x)
        ln_kernel<true><<<M_ROWS, 256, 0, stream>>>(tmp, x, x, g, bb);
    }

    // final LN -> tmp
    ln_kernel<false><<<M_ROWS, 256, 0, stream>>>(nullptr, x, tmp, fn_g, fn_b);

    // cast xf -> bf16 (reuse xb)
    int n4 = M_ROWS * D_MODEL / 4;
    cast_kernel<<<(n4 + 255) / 256, 256, 0, stream>>>(tmp, xb, n4);

    // logits = xf @ fc_w^T + fc_b   (2048 x 32000, K=1024)  [bf16 MFMA]
    gemm_bf16_nt<2><<<dim3(VOCAB / 128, M_ROWS / 128), 256, 0, stream>>>(
        xb, D_MODEL, wb_fc, D_MODEL, logits, VOCAB, D_MODEL, fc_b);
}

// Round 3
// 1451.439 us; speedup vs baseline: 4.7649x; 1.5623x over previous
//
#include <hip/hip_runtime.h>
#include <cstddef>
#include <cstdint>

#define D_MODEL 1024
#define D_INNER 2048
#define DT_RANK 64
#define D_STATE 8
#define NLAYERS 4
#define BATCH 2
#define SEQ 1024
#define M_ROWS (BATCH*SEQ)   /* 2048 */
#define VOCAB 32000
#define NC 32     /* scan chunks */
#define LC 32     /* chunk length (NC*LC == SEQ) */

typedef __attribute__((ext_vector_type(8))) short short8;
typedef __attribute__((ext_vector_type(4))) float f32x4;

__device__ __forceinline__ float sigmoidf_(float x) { return 1.f / (1.f + __expf(-x)); }

__device__ __forceinline__ unsigned short f2bf(float f) {
    unsigned u = __float_as_uint(f);
    u += 0x7fffu + ((u >> 16) & 1u);         // round-to-nearest-even
    return (unsigned short)(u >> 16);
}

// ---------------------------------------------------------------------------
// fp32 -> bf16 cast (weights only now), 4 elems/thread.
// ---------------------------------------------------------------------------
__global__ __launch_bounds__(256) void cast_kernel(const float* __restrict__ in,
                                                   unsigned short* __restrict__ out, int n4)
{
    int i = blockIdx.x * 256 + threadIdx.x;
    if (i >= n4) return;
    float4 v = ((const float4*)in)[i];
    ushort4 o;
    o.x = f2bf(v.x); o.y = f2bf(v.y); o.z = f2bf(v.z); o.w = f2bf(v.w);
    ((ushort4*)out)[i] = o;
}

// ---------------------------------------------------------------------------
// Embedding gather -> x (fp32) and xb (bf16)
// ---------------------------------------------------------------------------
__global__ __launch_bounds__(256) void gather_kernel(const int* __restrict__ ids,
                                                     const float* __restrict__ embed,
                                                     float* __restrict__ x,
                                                     unsigned short* __restrict__ xb)
{
    int m = blockIdx.x;
    int t = threadIdx.x;
    int id = ids[m];
    float4 v = ((const float4*)(embed + (size_t)id * D_MODEL))[t];
    ((float4*)(x + (size_t)m * D_MODEL))[t] = v;
    ushort4 o;
    o.x = f2bf(v.x); o.y = f2bf(v.y); o.z = f2bf(v.z); o.w = f2bf(v.w);
    ((ushort4*)(xb + (size_t)m * D_MODEL))[t] = o;
}

// ---------------------------------------------------------------------------
// bf16 MFMA GEMM  C[M,N] = A[M,K] * B[N,K]^T  (fp32 out)
// 128x128 tile, BK=32, 256 thr = 4 waves. EPI: 0 none, 2 +bias[col].
// ---------------------------------------------------------------------------
template<int EPI>
__global__ __launch_bounds__(256) void gemm_bf16_nt(const unsigned short* __restrict__ A, int lda,
                                                    const unsigned short* __restrict__ B, int ldb,
                                                    float* __restrict__ C, int ldc,
                                                    int K, const float* __restrict__ bias)
{
    __shared__ unsigned short As[128 * 32];
    __shared__ unsigned short Bs[128 * 32];
    const int tid = threadIdx.x;
    const int bm = blockIdx.y * 128, bn = blockIdx.x * 128;
    const int wid = tid >> 6, lane = tid & 63;
    const int wm = (wid >> 1) * 64, wn = (wid & 1) * 64;
    const int lrow = lane & 15, lkg = lane >> 4;

    const int srow = tid >> 2;
    const int skg = tid & 3;
    const unsigned short* Ag = A + (size_t)(bm + srow) * lda + skg * 8;
    const unsigned short* Bg = B + (size_t)(bn + srow) * ldb + skg * 8;
    unsigned short* Al = As + tid * 8;
    unsigned short* Bl = Bs + tid * 8;
    const size_t a64 = (size_t)64 * lda;
    const size_t b64 = (size_t)64 * ldb;

    f32x4 acc[4][4];
    #pragma unroll
    for (int i = 0; i < 4; ++i)
        #pragma unroll
        for (int j = 0; j < 4; ++j)
            acc[i][j] = f32x4{0.f, 0.f, 0.f, 0.f};

    for (int k0 = 0; k0 < K; k0 += 32) {
        __builtin_amdgcn_global_load_lds((const __attribute__((address_space(1))) void*)(Ag + k0),
                                         (__attribute__((address_space(3))) void*)Al, 16, 0, 0);
        __builtin_amdgcn_global_load_lds((const __attribute__((address_space(1))) void*)(Ag + a64 + k0),
                                         (__attribute__((address_space(3))) void*)(Al + 2048), 16, 0, 0);
        __builtin_amdgcn_global_load_lds((const __attribute__((address_space(1))) void*)(Bg + k0),
                                         (__attribute__((address_space(3))) void*)Bl, 16, 0, 0);
        __builtin_amdgcn_global_load_lds((const __attribute__((address_space(1))) void*)(Bg + b64 + k0),
                                         (__attribute__((address_space(3))) void*)(Bl + 2048), 16, 0, 0);
        __syncthreads();

        short8 af[4], bf[4];
        #pragma unroll
        for (int i = 0; i < 4; ++i)
            af[i] = *(const short8*)(As + (wm + 16 * i + lrow) * 32 + lkg * 8);
        #pragma unroll
        for (int j = 0; j < 4; ++j)
            bf[j] = *(const short8*)(Bs + (wn + 16 * j + lrow) * 32 + lkg * 8);
        #pragma unroll
        for (int i = 0; i < 4; ++i)
            #pragma unroll
            for (int j = 0; j < 4; ++j)
                acc[i][j] = __builtin_amdgcn_mfma_f32_16x16x32_bf16(af[i], bf[j], acc[i][j], 0, 0, 0);
        __syncthreads();
    }

    const int crow = bm + wm + lkg * 4;
    const int ccol = bn + wn + lrow;
    #pragma unroll
    for (int i = 0; i < 4; ++i) {
        #pragma unroll
        for (int j = 0; j < 4; ++j) {
            float bv = (EPI == 2) ? bias[ccol + 16 * j] : 0.f;
            float* Cp = C + (size_t)(crow + 16 * i) * ldc + ccol + 16 * j;
            #pragma unroll
            for (int r = 0; r < 4; ++r)
                Cp[(size_t)r * ldc] = acc[i][j][r] + bv;
        }
    }
}

// ---------------------------------------------------------------------------
// fp32 GEMM (small/odd shapes: x_proj N=80, dt K=64). EPI: 0 none, 1 bias+softplus
// ---------------------------------------------------------------------------
template<int EPI>
__global__ __launch_bounds__(256) void gemm_nt(const float* __restrict__ A, int lda,
                                               const float* __restrict__ B, int ldb,
                                               float* __restrict__ C, int ldc,
                                               int M, int N, int K,
                                               const float* __restrict__ bias)
{
    __shared__ float As[16][68];
    __shared__ float Bs[16][68];
    const int bm = blockIdx.y * 64, bn = blockIdx.x * 64;
    const int tid = threadIdx.x;
    const int tx = tid & 15, ty = tid >> 4;
    const int lr = tid >> 2;
    const int lk = (tid & 3) << 2;

    float acc[4][4] = {};

    for (int k0 = 0; k0 < K; k0 += 16) {
        float4 av = make_float4(0.f, 0.f, 0.f, 0.f);
        float4 bv = make_float4(0.f, 0.f, 0.f, 0.f);
        int arow = bm + lr;
        if (arow < M) av = *(const float4*)(A + (size_t)arow * lda + k0 + lk);
        int brow = bn + lr;
        if (brow < N) bv = *(const float4*)(B + (size_t)brow * ldb + k0 + lk);
        As[lk + 0][lr] = av.x; As[lk + 1][lr] = av.y; As[lk + 2][lr] = av.z; As[lk + 3][lr] = av.w;
        Bs[lk + 0][lr] = bv.x; Bs[lk + 1][lr] = bv.y; Bs[lk + 2][lr] = bv.z; Bs[lk + 3][lr] = bv.w;
        __syncthreads();
        #pragma unroll
        for (int kk = 0; kk < 16; ++kk) {
            float a0 = As[kk][ty * 4 + 0], a1 = As[kk][ty * 4 + 1];
            float a2 = As[kk][ty * 4 + 2], a3 = As[kk][ty * 4 + 3];
            float b0 = Bs[kk][tx * 4 + 0], b1 = Bs[kk][tx * 4 + 1];
            float b2 = Bs[kk][tx * 4 + 2], b3 = Bs[kk][tx * 4 + 3];
            acc[0][0] += a0 * b0; acc[0][1] += a0 * b1; acc[0][2] += a0 * b2; acc[0][3] += a0 * b3;
            acc[1][0] += a1 * b0; acc[1][1] += a1 * b1; acc[1][2] += a1 * b2; acc[1][3] += a1 * b3;
            acc[2][0] += a2 * b0; acc[2][1] += a2 * b1; acc[2][2] += a2 * b2; acc[2][3] += a2 * b3;
            acc[3][0] += a3 * b0; acc[3][1] += a3 * b1; acc[3][2] += a3 * b2; acc[3][3] += a3 * b3;
        }
        __syncthreads();
    }

    #pragma unroll
    for (int i = 0; i < 4; ++i) {
        int row = bm + ty * 4 + i;
        if (row >= M) continue;
        #pragma unroll
        for (int j = 0; j < 4; ++j) {
            int col = bn + tx * 4 + j;
            if (col >= N) continue;
            float v = acc[i][j];
            if (EPI == 1) { v += bias[col]; v = (v > 20.f) ? v : log1pf(__expf(v)); }
            C[(size_t)row * ldc + col] = v;
        }
    }
}

// ---------------------------------------------------------------------------
// Causal depthwise conv1d (k=4) + bias + SiLU
// ---------------------------------------------------------------------------
__global__ __launch_bounds__(256) void conv_silu_kernel(const float* __restrict__ xz,
                                                        const float* __restrict__ cw,
                                                        const float* __restrict__ cb,
                                                        float* __restrict__ xc)
{
    int idx = blockIdx.x * 256 + threadIdx.x;
    int d = idx & (D_INNER - 1);
    int m = idx >> 11;
    int l = m & (SEQ - 1);
    int b = m >> 10;
    float w0 = cw[d * 4 + 0], w1 = cw[d * 4 + 1], w2 = cw[d * 4 + 2], w3 = cw[d * 4 + 3];
    float s = cb[d];
    const float* base = xz + ((size_t)b * SEQ) * (2 * D_INNER) + d;
    if (l - 3 >= 0) s += base[(size_t)(l - 3) * (2 * D_INNER)] * w0;
    if (l - 2 >= 0) s += base[(size_t)(l - 2) * (2 * D_INNER)] * w1;
    if (l - 1 >= 0) s += base[(size_t)(l - 1) * (2 * D_INNER)] * w2;
    s += base[(size_t)l * (2 * D_INNER)] * w3;
    xc[(size_t)m * D_INNER + d] = s * sigmoidf_(s);
}

// ---------------------------------------------------------------------------
// Chunk-parallel selective scan.
// Decomposition: h[l] = dA[l]*h[l-1] + dBu[l] is a linear recurrence.
// Phase A (scan_partial): per chunk c, local scan from h=0 -> H_c, P_c=prod(dA).
// Phase B (scan_combine): sequential over 32 chunks per (b,n,d); P becomes h0.
// Phase C (scan_final): re-scan chunk with true h0; fused D-skip + silu(z) gate,
//                       emits y in bf16.
// Thread owns one (b,chunk,d) with all 8 states in registers (no shuffles).
// blockIdx.x: bit0=b, bits1-5=chunk, bits6-8=dblk.  256 thr = 256 d's.
// ---------------------------------------------------------------------------
__global__ __launch_bounds__(256) void scan_partial(const float* __restrict__ dt,
                                                    const float* __restrict__ xdbl,
                                                    const float* __restrict__ xc,
                                                    const float* __restrict__ A_log,
                                                    float* __restrict__ H,
                                                    float* __restrict__ P)
{
    const int tid = threadIdx.x;
    const int b = blockIdx.x & 1;
    const int c = (blockIdx.x >> 1) & (NC - 1);
    const int d = ((blockIdx.x >> 6) << 8) + tid;

    __shared__ float Bs[LC][8];
    {
        int r = tid >> 3, n = tid & 7;    // 256 threads cover 32x8 exactly
        Bs[r][n] = xdbl[(size_t)(b * SEQ + c * LC + r) * 80 + DT_RANK + n];
    }
    __syncthreads();

    float An[8];
    #pragma unroll
    for (int n = 0; n < 8; ++n) An[n] = -__expf(A_log[d * 8 + n]);
    float h[8] = {0.f,0.f,0.f,0.f,0.f,0.f,0.f,0.f};
    float p[8] = {1.f,1.f,1.f,1.f,1.f,1.f,1.f,1.f};

    const float* dtp = dt + (size_t)(b * SEQ + c * LC) * D_INNER + d;
    const float* xcp = xc + (size_t)(b * SEQ + c * LC) * D_INNER + d;
    for (int l = 0; l < LC; ++l) {
        float dtv = dtp[(size_t)l * D_INNER];
        float ux  = dtv * xcp[(size_t)l * D_INNER];
        #pragma unroll
        for (int n = 0; n < 8; ++n) {
            float dA = __expf(dtv * An[n]);
            h[n] = dA * h[n] + Bs[l][n] * ux;
            p[n] *= dA;
        }
    }
    size_t base = (size_t)((b * NC + c) * 8) * D_INNER + d;
    #pragma unroll
    for (int n = 0; n < 8; ++n) {
        H[base + (size_t)n * D_INNER] = h[n];
        P[base + (size_t)n * D_INNER] = p[n];
    }
}

__global__ __launch_bounds__(256) void scan_combine(const float* __restrict__ H,
                                                    float* __restrict__ P /* -> h0 */)
{
    int idx = blockIdx.x * 256 + threadIdx.x;   // 32768 = 2*8*2048
    int d = idx & (D_INNER - 1);
    int n = (idx >> 11) & 7;
    int b = idx >> 14;
    float hp = 0.f;
    for (int c = 0; c < NC; ++c) {
        size_t base = (size_t)((b * NC + c) * 8 + n) * D_INNER + d;
        float Pv = P[base], Hv = H[base];
        P[base] = hp;                 // h0 for chunk c
        hp = Pv * hp + Hv;
    }
}

__global__ __launch_bounds__(256) void scan_final(const float* __restrict__ dt,
                                                  const float* __restrict__ xdbl,
                                                  const float* __restrict__ xc,
                                                  const float* __restrict__ xz,
                                                  const float* __restrict__ A_log,
                                                  const float* __restrict__ Dp,
                                                  const float* __restrict__ h0,
                                                  unsigned short* __restrict__ yb)
{
    const int tid = threadIdx.x;
    const int b = blockIdx.x & 1;
    const int c = (blockIdx.x >> 1) & (NC - 1);
    const int d = ((blockIdx.x >> 6) << 8) + tid;

    __shared__ float Bs[LC][8];
    __shared__ float Cs[LC][8];
    {
        int r = tid >> 3, n = tid & 7;
        size_t xrow = (size_t)(b * SEQ + c * LC + r) * 80;
        Bs[r][n] = xdbl[xrow + DT_RANK + n];
        Cs[r][n] = xdbl[xrow + DT_RANK + 8 + n];
    }
    __syncthreads();

    float An[8], h[8];
    size_t base = (size_t)((b * NC + c) * 8) * D_INNER + d;
    #pragma unroll
    for (int n = 0; n < 8; ++n) {
        An[n] = -__expf(A_log[d * 8 + n]);
        h[n] = h0[base + (size_t)n * D_INNER];
    }
    const float Dv = Dp[d];

    const float* dtp = dt + (size_t)(b * SEQ + c * LC) * D_INNER + d;
    const float* xcp = xc + (size_t)(b * SEQ + c * LC) * D_INNER + d;
    const float* zp  = xz + (size_t)(b * SEQ + c * LC) * (2 * D_INNER) + D_INNER + d;
    unsigned short* ybp = yb + (size_t)(b * SEQ + c * LC) * D_INNER + d;

    for (int l = 0; l < LC; ++l) {
        float dtv = dtp[(size_t)l * D_INNER];
        float xcv = xcp[(size_t)l * D_INNER];
        float zv  = zp[(size_t)l * (2 * D_INNER)];
        float ux = dtv * xcv;
        float acc = 0.f;
        #pragma unroll
        for (int n = 0; n < 8; ++n) {
            float dA = __expf(dtv * An[n]);
            h[n] = dA * h[n] + Bs[l][n] * ux;
            acc += h[n] * Cs[l][n];
        }
        float yv = (acc + xcv * Dv) * (zv * sigmoidf_(zv));
        ybp[(size_t)l * D_INNER] = f2bf(yv);
    }
}

// ---------------------------------------------------------------------------
// LayerNorm (1024). ADD: out = LN(extra + xin) else LN(xin). Emits fp32 + bf16.
// ---------------------------------------------------------------------------
template<bool ADD>
__global__ __launch_bounds__(256) void ln_kernel(const float* __restrict__ extra,
                                                 const float* __restrict__ xin,
                                                 float* __restrict__ xout,
                                                 unsigned short* __restrict__ xbout,
                                                 const float* __restrict__ g,
                                                 const float* __restrict__ bb)
{
    int m = blockIdx.x;
    int t = threadIdx.x;
    float4 v = ((const float4*)(xin + (size_t)m * D_MODEL))[t];
    if (ADD) {
        float4 e = ((const float4*)(extra + (size_t)m * D_MODEL))[t];
        v.x += e.x; v.y += e.y; v.z += e.z; v.w += e.w;
    }
    float s  = v.x + v.y + v.z + v.w;
    float s2 = v.x * v.x + v.y * v.y + v.z * v.z + v.w * v.w;
    for (int off = 32; off; off >>= 1) {
        s  += __shfl_down(s, off);
        s2 += __shfl_down(s2, off);
    }
    __shared__ float red[8];
    int wid = t >> 6, lane = t & 63;
    if (lane == 0) { red[wid] = s; red[wid + 4] = s2; }
    __syncthreads();
    if (t == 0) {
        float a  = red[0] + red[1] + red[2] + red[3];
        float b2 = red[4] + red[5] + red[6] + red[7];
        float mu = a * (1.f / D_MODEL);
        red[0] = mu;
        red[4] = b2 * (1.f / D_MODEL) - mu * mu;
    }
    __syncthreads();
    float mu = red[0];
    float rs = rsqrtf(red[4] + 1e-5f);
    float4 gg = ((const float4*)g)[t];
    float4 bv = ((const float4*)bb)[t];
    float4 o;
    o.x = (v.x - mu) * rs * gg.x + bv.x;
    o.y = (v.y - mu) * rs * gg.y + bv.y;
    o.z = (v.z - mu) * rs * gg.z + bv.z;
    o.w = (v.w - mu) * rs * gg.w + bv.w;
    ((float4*)(xout + (size_t)m * D_MODEL))[t] = o;
    ushort4 ob;
    ob.x = f2bf(o.x); ob.y = f2bf(o.y); ob.z = f2bf(o.z); ob.w = f2bf(o.w);
    ((ushort4*)(xbout + (size_t)m * D_MODEL))[t] = ob;
}

// ---------------------------------------------------------------------------
extern "C" void kernel_launch(void* const* d_in, const int* in_sizes, int n_in,
                              void* d_out, int out_size, void* d_ws, size_t ws_size,
                              hipStream_t stream)
{
    const int*   ids      = (const int*)d_in[0];
    const float* embed    = (const float*)d_in[1];
    const float* in_proj  = (const float*)d_in[2];
    const float* conv_w   = (const float*)d_in[3];
    const float* conv_b   = (const float*)d_in[4];
    const float* x_proj   = (const float*)d_in[5];
    const float* dt_w     = (const float*)d_in[6];
    const float* dt_b     = (const float*)d_in[7];
    const float* A_log    = (const float*)d_in[8];
    const float* Dp       = (const float*)d_in[9];
    const float* out_proj = (const float*)d_in[10];
    const float* ln_g     = (const float*)d_in[11];
    const float* ln_b     = (const float*)d_in[12];
    const float* fn_g     = (const float*)d_in[13];
    const float* fn_b     = (const float*)d_in[14];
    const float* fc_w     = (const float*)d_in[15];
    const float* fc_b     = (const float*)d_in[16];
    float* logits = (float*)d_out;

    // ---- workspace layout ----
    float* ws = (float*)d_ws;
    float* x     = ws;                                   // 2048*1024
    float* xz    = x + (size_t)M_ROWS * D_MODEL;         // 2048*4096
    float* xc    = xz + (size_t)M_ROWS * 2 * D_INNER;    // 2048*2048
    float* xdbl  = xc + (size_t)M_ROWS * D_INNER;        // 2048*80
    float* dtbuf = xdbl + (size_t)M_ROWS * 80;           // 2048*2048
    float* tmp   = dtbuf + (size_t)M_ROWS * D_INNER;     // 2048*1024

    // scan H/P alias tmp exactly: 2 * (2*32*8*2048) = 2*1048576 = 2097152 = |tmp|
    float* Hbuf = tmp;
    float* Pbuf = tmp + (size_t)BATCH * NC * D_STATE * D_INNER;

    unsigned short* xb    = (unsigned short*)(tmp + (size_t)M_ROWS * D_MODEL);
    unsigned short* yb    = xb + (size_t)M_ROWS * D_MODEL;
    unsigned short* wb_in = yb + (size_t)M_ROWS * D_INNER;
    unsigned short* wb_out= wb_in + (size_t)NLAYERS * 2 * D_INNER * D_MODEL;
    unsigned short* wb_fc = wb_out + (size_t)NLAYERS * D_MODEL * D_INNER;

    // ---- weight casts ----
    {
        int n4 = NLAYERS * 2 * D_INNER * D_MODEL / 4;
        cast_kernel<<<(n4 + 255) / 256, 256, 0, stream>>>(in_proj, wb_in, n4);
        n4 = NLAYERS * D_MODEL * D_INNER / 4;
        cast_kernel<<<(n4 + 255) / 256, 256, 0, stream>>>(out_proj, wb_out, n4);
        n4 = VOCAB * D_MODEL / 4;
        cast_kernel<<<(n4 + 255) / 256, 256, 0, stream>>>(fc_w, wb_fc, n4);
    }

    // ---- embedding (fp32 + bf16) ----
    gather_kernel<<<M_ROWS, 256, 0, stream>>>(ids, embed, x, xb);

    for (int i = 0; i < NLAYERS; ++i) {
        const unsigned short* W_in_b  = wb_in + (size_t)i * 2 * D_INNER * D_MODEL;
        const unsigned short* W_out_b = wb_out + (size_t)i * D_MODEL * D_INNER;
        const float* cw    = conv_w + (size_t)i * D_INNER * 4;
        const float* cb    = conv_b + (size_t)i * D_INNER;
        const float* W_x   = x_proj + (size_t)i * 80 * D_INNER;
        const float* W_dt  = dt_w + (size_t)i * D_INNER * DT_RANK;
        const float* b_dt  = dt_b + (size_t)i * D_INNER;
        const float* Al    = A_log + (size_t)i * D_INNER * D_STATE;
        const float* Dl    = Dp + (size_t)i * D_INNER;
        const float* g     = ln_g + (size_t)i * D_MODEL;
        const float* bb    = ln_b + (size_t)i * D_MODEL;

        // xz = x @ in_proj^T   (2048 x 4096, K=1024)  [bf16 MFMA]
        gemm_bf16_nt<0><<<dim3(2 * D_INNER / 128, M_ROWS / 128), 256, 0, stream>>>(
            xb, D_MODEL, W_in_b, D_MODEL, xz, 2 * D_INNER, D_MODEL, nullptr);

        // xc = silu(conv(xz[:, :2048]) + cb)
        conv_silu_kernel<<<(M_ROWS * D_INNER) / 256, 256, 0, stream>>>(xz, cw, cb, xc);

        // x_dbl = xc @ x_proj^T   (2048 x 80, K=2048)  [fp32]
        gemm_nt<0><<<dim3((80 + 63) / 64, M_ROWS / 64), 256, 0, stream>>>(
            xc, D_INNER, W_x, D_INNER, xdbl, 80, M_ROWS, 80, D_INNER, nullptr);

        // dt = softplus(x_dbl[:, :64] @ dt_w^T + b_dt)  [fp32]
        gemm_nt<1><<<dim3(D_INNER / 64, M_ROWS / 64), 256, 0, stream>>>(
            xdbl, 80, W_dt, DT_RANK, dtbuf, D_INNER, M_ROWS, D_INNER, DT_RANK, b_dt);

        // chunk-parallel scan -> yb (bf16)
        scan_partial<<<BATCH * NC * (D_INNER / 256), 256, 0, stream>>>(
            dtbuf, xdbl, xc, Al, Hbuf, Pbuf);
        scan_combine<<<(BATCH * D_STATE * D_INNER) / 256, 256, 0, stream>>>(Hbuf, Pbuf);
        scan_final<<<BATCH * NC * (D_INNER / 256), 256, 0, stream>>>(
            dtbuf, xdbl, xc, xz, Al, Dl, Pbuf, yb);

        // tmp = y @ out_proj^T   (2048 x 1024, K=2048)  [bf16 MFMA]
        gemm_bf16_nt<0><<<dim3(D_MODEL / 128, M_ROWS / 128), 256, 0, stream>>>(
            yb, D_INNER, W_out_b, D_INNER, tmp, D_MODEL, D_INNER, nullptr);

        // x = LN(tmp + x)  (fp32 + bf16)
        ln_kernel<true><<<M_ROWS, 256, 0, stream>>>(tmp, x, x, xb, g, bb);
    }

    // final LN -> tmp + xb
    ln_kernel<false><<<M_ROWS, 256, 0, stream>>>(nullptr, x, tmp, xb, fn_g, fn_b);

    // logits = xf @ fc_w^T + fc_b   (2048 x 32000, K=1024)  [bf16 MFMA]
    gemm_bf16_nt<2><<<dim3(VOCAB / 128, M_ROWS / 128), 256, 0, stream>>>(
        xb, D_MODEL, wb_fc, D_MODEL, logits, VOCAB, D_MODEL, fc_b);
}

// Round 4
// 1175.784 us; speedup vs baseline: 5.8820x; 1.2344x over previous
//
#include <hip/hip_runtime.h>
#include <cstddef>
#include <cstdint>

#define D_MODEL 1024
#define D_INNER 2048
#define DT_RANK 64
#define D_STATE 8
#define NLAYERS 4
#define BATCH 2
#define SEQ 1024
#define M_ROWS (BATCH*SEQ)   /* 2048 */
#define VOCAB 32000
#define XPAD 128             /* x_proj N padded 80 -> 128 */
#define NC 32                /* scan chunks */
#define LC 32                /* chunk length (NC*LC == SEQ) */

typedef __attribute__((ext_vector_type(8))) short short8;
typedef __attribute__((ext_vector_type(4))) float f32x4;

__device__ __forceinline__ float sigmoidf_(float x) { return 1.f / (1.f + __expf(-x)); }

__device__ __forceinline__ unsigned short f2bf(float f) {
    unsigned u = __float_as_uint(f);
    u += 0x7fffu + ((u >> 16) & 1u);         // round-to-nearest-even
    return (unsigned short)(u >> 16);
}

// ---------------------------------------------------------------------------
// fp32 -> bf16 cast (contiguous), 4 elems/thread.
// ---------------------------------------------------------------------------
__global__ __launch_bounds__(256) void cast_kernel(const float* __restrict__ in,
                                                   unsigned short* __restrict__ out, int n4)
{
    int i = blockIdx.x * 256 + threadIdx.x;
    if (i >= n4) return;
    float4 v = ((const float4*)in)[i];
    ushort4 o;
    o.x = f2bf(v.x); o.y = f2bf(v.y); o.z = f2bf(v.z); o.w = f2bf(v.w);
    ((ushort4*)out)[i] = o;
}

// ---------------------------------------------------------------------------
// x_proj weight: cast 4x(80,2048) fp32 -> 4x(128,2048) bf16, rows 80..127 = 0
// ---------------------------------------------------------------------------
__global__ __launch_bounds__(256) void cast_pad_xproj(const float* __restrict__ in,
                                                      unsigned short* __restrict__ out)
{
    int i = blockIdx.x * 256 + threadIdx.x;     // over 4*128*2048/4 = 262144
    if (i >= NLAYERS * XPAD * D_INNER / 4) return;
    int col4 = i & (D_INNER / 4 - 1);           // 512 col-groups
    int row = (i >> 9) & (XPAD - 1);
    int layer = i >> 16;
    ushort4 o = {0, 0, 0, 0};
    if (row < 80) {
        float4 v = ((const float4*)(in + ((size_t)layer * 80 + row) * D_INNER))[col4];
        o.x = f2bf(v.x); o.y = f2bf(v.y); o.z = f2bf(v.z); o.w = f2bf(v.w);
    }
    ((ushort4*)out)[i] = o;
}

// ---------------------------------------------------------------------------
// Embedding gather -> x (fp32) and xb (bf16)
// ---------------------------------------------------------------------------
__global__ __launch_bounds__(256) void gather_kernel(const int* __restrict__ ids,
                                                     const float* __restrict__ embed,
                                                     float* __restrict__ x,
                                                     unsigned short* __restrict__ xb)
{
    int m = blockIdx.x;
    int t = threadIdx.x;
    int id = ids[m];
    float4 v = ((const float4*)(embed + (size_t)id * D_MODEL))[t];
    ((float4*)(x + (size_t)m * D_MODEL))[t] = v;
    ushort4 o;
    o.x = f2bf(v.x); o.y = f2bf(v.y); o.z = f2bf(v.z); o.w = f2bf(v.w);
    ((ushort4*)(xb + (size_t)m * D_MODEL))[t] = o;
}

// ---------------------------------------------------------------------------
// bf16 MFMA GEMM  C[M,N] = A[M,K] * B[N,K]^T  (fp32 out)
// 128x128 tile, BK=32, 256 thr = 4 waves.
// Grid: dim3(M/128, N/128) -- M is the FAST dim; bijective XCD chunk swizzle
// (requires gridDim.x*gridDim.y % 8 == 0) so consecutive blocks on one XCD
// share the B panel (L2 locality).
// EPI: 0 none | 1 +bias,softplus | 2 +bias | 3 none + bf16 copy to Cb
// ---------------------------------------------------------------------------
template<int EPI>
__global__ __launch_bounds__(256) void gemm_bf16_nt(const unsigned short* __restrict__ A, int lda,
                                                    const unsigned short* __restrict__ B, int ldb,
                                                    float* __restrict__ C, int ldc,
                                                    int K, const float* __restrict__ bias,
                                                    unsigned short* __restrict__ Cb)
{
    __shared__ unsigned short As[128 * 32];
    __shared__ unsigned short Bs[128 * 32];
    const int tid = threadIdx.x;

    const int gm = gridDim.x;
    const int bid = blockIdx.y * gm + blockIdx.x;
    const int q = (gm * gridDim.y) >> 3;           // nwg % 8 == 0 guaranteed
    const int swz = (bid & 7) * q + (bid >> 3);
    const int bm = (swz % gm) * 128, bn = (swz / gm) * 128;

    const int wid = tid >> 6, lane = tid & 63;
    const int wm = (wid >> 1) * 64, wn = (wid & 1) * 64;
    const int lrow = lane & 15, lkg = lane >> 4;

    const int srow = tid >> 2;
    const int skg = tid & 3;
    const unsigned short* Ag = A + (size_t)(bm + srow) * lda + skg * 8;
    const unsigned short* Bg = B + (size_t)(bn + srow) * ldb + skg * 8;
    unsigned short* Al = As + tid * 8;
    unsigned short* Bl = Bs + tid * 8;
    const size_t a64 = (size_t)64 * lda;
    const size_t b64 = (size_t)64 * ldb;

    f32x4 acc[4][4];
    #pragma unroll
    for (int i = 0; i < 4; ++i)
        #pragma unroll
        for (int j = 0; j < 4; ++j)
            acc[i][j] = f32x4{0.f, 0.f, 0.f, 0.f};

    for (int k0 = 0; k0 < K; k0 += 32) {
        __builtin_amdgcn_global_load_lds((const __attribute__((address_space(1))) void*)(Ag + k0),
                                         (__attribute__((address_space(3))) void*)Al, 16, 0, 0);
        __builtin_amdgcn_global_load_lds((const __attribute__((address_space(1))) void*)(Ag + a64 + k0),
                                         (__attribute__((address_space(3))) void*)(Al + 2048), 16, 0, 0);
        __builtin_amdgcn_global_load_lds((const __attribute__((address_space(1))) void*)(Bg + k0),
                                         (__attribute__((address_space(3))) void*)Bl, 16, 0, 0);
        __builtin_amdgcn_global_load_lds((const __attribute__((address_space(1))) void*)(Bg + b64 + k0),
                                         (__attribute__((address_space(3))) void*)(Bl + 2048), 16, 0, 0);
        __syncthreads();

        short8 af[4], bf[4];
        #pragma unroll
        for (int i = 0; i < 4; ++i)
            af[i] = *(const short8*)(As + (wm + 16 * i + lrow) * 32 + lkg * 8);
        #pragma unroll
        for (int j = 0; j < 4; ++j)
            bf[j] = *(const short8*)(Bs + (wn + 16 * j + lrow) * 32 + lkg * 8);
        #pragma unroll
        for (int i = 0; i < 4; ++i)
            #pragma unroll
            for (int j = 0; j < 4; ++j)
                acc[i][j] = __builtin_amdgcn_mfma_f32_16x16x32_bf16(af[i], bf[j], acc[i][j], 0, 0, 0);
        __syncthreads();
    }

    const int crow = bm + wm + lkg * 4;
    const int ccol = bn + wn + lrow;
    #pragma unroll
    for (int i = 0; i < 4; ++i) {
        #pragma unroll
        for (int j = 0; j < 4; ++j) {
            float bv = (EPI == 1 || EPI == 2) ? bias[ccol + 16 * j] : 0.f;
            float* Cp = C + (size_t)(crow + 16 * i) * ldc + ccol + 16 * j;
            unsigned short* Cbp = (EPI == 3) ? (Cb + (size_t)(crow + 16 * i) * ldc + ccol + 16 * j)
                                             : (unsigned short*)nullptr;
            #pragma unroll
            for (int r = 0; r < 4; ++r) {
                float v = acc[i][j][r] + bv;
                if (EPI == 1) v = (v > 20.f) ? v : log1pf(__expf(v));
                Cp[(size_t)r * ldc] = v;
                if (EPI == 3) Cbp[(size_t)r * ldc] = f2bf(v);
            }
        }
    }
}

// ---------------------------------------------------------------------------
// Causal depthwise conv1d (k=4) + bias + SiLU -> xc (fp32) and xcb (bf16)
// ---------------------------------------------------------------------------
__global__ __launch_bounds__(256) void conv_silu_kernel(const float* __restrict__ xz,
                                                        const float* __restrict__ cw,
                                                        const float* __restrict__ cb,
                                                        float* __restrict__ xc,
                                                        unsigned short* __restrict__ xcb)
{
    int idx = blockIdx.x * 256 + threadIdx.x;
    int d = idx & (D_INNER - 1);
    int m = idx >> 11;
    int l = m & (SEQ - 1);
    int b = m >> 10;
    float w0 = cw[d * 4 + 0], w1 = cw[d * 4 + 1], w2 = cw[d * 4 + 2], w3 = cw[d * 4 + 3];
    float s = cb[d];
    const float* base = xz + ((size_t)b * SEQ) * (2 * D_INNER) + d;
    if (l - 3 >= 0) s += base[(size_t)(l - 3) * (2 * D_INNER)] * w0;
    if (l - 2 >= 0) s += base[(size_t)(l - 2) * (2 * D_INNER)] * w1;
    if (l - 1 >= 0) s += base[(size_t)(l - 1) * (2 * D_INNER)] * w2;
    s += base[(size_t)l * (2 * D_INNER)] * w3;
    float v = s * sigmoidf_(s);
    xc[(size_t)m * D_INNER + d] = v;
    xcb[(size_t)m * D_INNER + d] = f2bf(v);
}

// ---------------------------------------------------------------------------
// Chunk-parallel selective scan (linear recurrence decomposition).
// A: per-chunk local scan from 0 -> H_c, P_c=prod(dA).  B: serial combine
// over 32 chunks -> per-chunk h0 (in-place over P).  C: re-scan with h0,
// fused D-skip + silu(z) gate, emits y bf16.
// xdbl row stride = XPAD(128); B at col 64, C at col 72.
// ---------------------------------------------------------------------------
__global__ __launch_bounds__(256) void scan_partial(const float* __restrict__ dt,
                                                    const float* __restrict__ xdbl,
                                                    const float* __restrict__ xc,
                                                    const float* __restrict__ A_log,
                                                    float* __restrict__ H,
                                                    float* __restrict__ P)
{
    const int tid = threadIdx.x;
    const int b = blockIdx.x & 1;
    const int c = (blockIdx.x >> 1) & (NC - 1);
    const int d = ((blockIdx.x >> 6) << 8) + tid;

    __shared__ float Bs[LC][8];
    {
        int r = tid >> 3, n = tid & 7;
        Bs[r][n] = xdbl[(size_t)(b * SEQ + c * LC + r) * XPAD + DT_RANK + n];
    }
    __syncthreads();

    float An[8];
    #pragma unroll
    for (int n = 0; n < 8; ++n) An[n] = -__expf(A_log[d * 8 + n]);
    float h[8] = {0.f,0.f,0.f,0.f,0.f,0.f,0.f,0.f};
    float p[8] = {1.f,1.f,1.f,1.f,1.f,1.f,1.f,1.f};

    const float* dtp = dt + (size_t)(b * SEQ + c * LC) * D_INNER + d;
    const float* xcp = xc + (size_t)(b * SEQ + c * LC) * D_INNER + d;
    for (int l = 0; l < LC; ++l) {
        float dtv = dtp[(size_t)l * D_INNER];
        float ux  = dtv * xcp[(size_t)l * D_INNER];
        #pragma unroll
        for (int n = 0; n < 8; ++n) {
            float dA = __expf(dtv * An[n]);
            h[n] = dA * h[n] + Bs[l][n] * ux;
            p[n] *= dA;
        }
    }
    size_t base = (size_t)((b * NC + c) * 8) * D_INNER + d;
    #pragma unroll
    for (int n = 0; n < 8; ++n) {
        H[base + (size_t)n * D_INNER] = h[n];
        P[base + (size_t)n * D_INNER] = p[n];
    }
}

__global__ __launch_bounds__(256) void scan_combine(const float* __restrict__ H,
                                                    float* __restrict__ P /* -> h0 */)
{
    int idx = blockIdx.x * 256 + threadIdx.x;   // 32768 = 2*8*2048
    int d = idx & (D_INNER - 1);
    int n = (idx >> 11) & 7;
    int b = idx >> 14;
    float hp = 0.f;
    for (int c = 0; c < NC; ++c) {
        size_t base = (size_t)((b * NC + c) * 8 + n) * D_INNER + d;
        float Pv = P[base], Hv = H[base];
        P[base] = hp;
        hp = Pv * hp + Hv;
    }
}

__global__ __launch_bounds__(256) void scan_final(const float* __restrict__ dt,
                                                  const float* __restrict__ xdbl,
                                                  const float* __restrict__ xc,
                                                  const float* __restrict__ xz,
                                                  const float* __restrict__ A_log,
                                                  const float* __restrict__ Dp,
                                                  const float* __restrict__ h0,
                                                  unsigned short* __restrict__ yb)
{
    const int tid = threadIdx.x;
    const int b = blockIdx.x & 1;
    const int c = (blockIdx.x >> 1) & (NC - 1);
    const int d = ((blockIdx.x >> 6) << 8) + tid;

    __shared__ float Bs[LC][8];
    __shared__ float Cs[LC][8];
    {
        int r = tid >> 3, n = tid & 7;
        size_t xrow = (size_t)(b * SEQ + c * LC + r) * XPAD;
        Bs[r][n] = xdbl[xrow + DT_RANK + n];
        Cs[r][n] = xdbl[xrow + DT_RANK + 8 + n];
    }
    __syncthreads();

    float An[8], h[8];
    size_t base = (size_t)((b * NC + c) * 8) * D_INNER + d;
    #pragma unroll
    for (int n = 0; n < 8; ++n) {
        An[n] = -__expf(A_log[d * 8 + n]);
        h[n] = h0[base + (size_t)n * D_INNER];
    }
    const float Dv = Dp[d];

    const float* dtp = dt + (size_t)(b * SEQ + c * LC) * D_INNER + d;
    const float* xcp = xc + (size_t)(b * SEQ + c * LC) * D_INNER + d;
    const float* zp  = xz + (size_t)(b * SEQ + c * LC) * (2 * D_INNER) + D_INNER + d;
    unsigned short* ybp = yb + (size_t)(b * SEQ + c * LC) * D_INNER + d;

    for (int l = 0; l < LC; ++l) {
        float dtv = dtp[(size_t)l * D_INNER];
        float xcv = xcp[(size_t)l * D_INNER];
        float zv  = zp[(size_t)l * (2 * D_INNER)];
        float ux = dtv * xcv;
        float acc = 0.f;
        #pragma unroll
        for (int n = 0; n < 8; ++n) {
            float dA = __expf(dtv * An[n]);
            h[n] = dA * h[n] + Bs[l][n] * ux;
            acc += h[n] * Cs[l][n];
        }
        float yv = (acc + xcv * Dv) * (zv * sigmoidf_(zv));
        ybp[(size_t)l * D_INNER] = f2bf(yv);
    }
}

// ---------------------------------------------------------------------------
// LayerNorm (1024). ADD: out = LN(extra + xin) else LN(xin). Emits fp32 + bf16.
// ---------------------------------------------------------------------------
template<bool ADD>
__global__ __launch_bounds__(256) void ln_kernel(const float* __restrict__ extra,
                                                 const float* __restrict__ xin,
                                                 float* __restrict__ xout,
                                                 unsigned short* __restrict__ xbout,
                                                 const float* __restrict__ g,
                                                 const float* __restrict__ bb)
{
    int m = blockIdx.x;
    int t = threadIdx.x;
    float4 v = ((const float4*)(xin + (size_t)m * D_MODEL))[t];
    if (ADD) {
        float4 e = ((const float4*)(extra + (size_t)m * D_MODEL))[t];
        v.x += e.x; v.y += e.y; v.z += e.z; v.w += e.w;
    }
    float s  = v.x + v.y + v.z + v.w;
    float s2 = v.x * v.x + v.y * v.y + v.z * v.z + v.w * v.w;
    for (int off = 32; off; off >>= 1) {
        s  += __shfl_down(s, off);
        s2 += __shfl_down(s2, off);
    }
    __shared__ float red[8];
    int wid = t >> 6, lane = t & 63;
    if (lane == 0) { red[wid] = s; red[wid + 4] = s2; }
    __syncthreads();
    if (t == 0) {
        float a  = red[0] + red[1] + red[2] + red[3];
        float b2 = red[4] + red[5] + red[6] + red[7];
        float mu = a * (1.f / D_MODEL);
        red[0] = mu;
        red[4] = b2 * (1.f / D_MODEL) - mu * mu;
    }
    __syncthreads();
    float mu = red[0];
    float rs = rsqrtf(red[4] + 1e-5f);
    float4 gg = ((const float4*)g)[t];
    float4 bv = ((const float4*)bb)[t];
    float4 o;
    o.x = (v.x - mu) * rs * gg.x + bv.x;
    o.y = (v.y - mu) * rs * gg.y + bv.y;
    o.z = (v.z - mu) * rs * gg.z + bv.z;
    o.w = (v.w - mu) * rs * gg.w + bv.w;
    ((float4*)(xout + (size_t)m * D_MODEL))[t] = o;
    ushort4 ob;
    ob.x = f2bf(o.x); ob.y = f2bf(o.y); ob.z = f2bf(o.z); ob.w = f2bf(o.w);
    ((ushort4*)(xbout + (size_t)m * D_MODEL))[t] = ob;
}

// ---------------------------------------------------------------------------
extern "C" void kernel_launch(void* const* d_in, const int* in_sizes, int n_in,
                              void* d_out, int out_size, void* d_ws, size_t ws_size,
                              hipStream_t stream)
{
    const int*   ids      = (const int*)d_in[0];
    const float* embed    = (const float*)d_in[1];
    const float* in_proj  = (const float*)d_in[2];
    const float* conv_w   = (const float*)d_in[3];
    const float* conv_b   = (const float*)d_in[4];
    const float* x_proj   = (const float*)d_in[5];
    const float* dt_w     = (const float*)d_in[6];
    const float* dt_b     = (const float*)d_in[7];
    const float* A_log    = (const float*)d_in[8];
    const float* Dp       = (const float*)d_in[9];
    const float* out_proj = (const float*)d_in[10];
    const float* ln_g     = (const float*)d_in[11];
    const float* ln_b     = (const float*)d_in[12];
    const float* fn_g     = (const float*)d_in[13];
    const float* fn_b     = (const float*)d_in[14];
    const float* fc_w     = (const float*)d_in[15];
    const float* fc_b     = (const float*)d_in[16];
    float* logits = (float*)d_out;

    // ---- workspace layout ----
    float* ws = (float*)d_ws;
    float* x     = ws;                                   // 2048*1024
    float* xz    = x + (size_t)M_ROWS * D_MODEL;         // 2048*4096
    float* xc    = xz + (size_t)M_ROWS * 2 * D_INNER;    // 2048*2048
    float* xdbl  = xc + (size_t)M_ROWS * D_INNER;        // 2048*128
    float* dtbuf = xdbl + (size_t)M_ROWS * XPAD;         // 2048*2048
    float* tmp   = dtbuf + (size_t)M_ROWS * D_INNER;     // 2048*1024

    float* Hbuf = tmp;
    float* Pbuf = tmp + (size_t)BATCH * NC * D_STATE * D_INNER;

    unsigned short* xb     = (unsigned short*)(tmp + (size_t)M_ROWS * D_MODEL);
    unsigned short* yb     = xb + (size_t)M_ROWS * D_MODEL;
    unsigned short* xcb    = yb + (size_t)M_ROWS * D_INNER;
    unsigned short* xdbl_b = xcb + (size_t)M_ROWS * D_INNER;
    unsigned short* wb_in  = xdbl_b + (size_t)M_ROWS * XPAD;
    unsigned short* wb_out = wb_in + (size_t)NLAYERS * 2 * D_INNER * D_MODEL;
    unsigned short* wb_fc  = wb_out + (size_t)NLAYERS * D_MODEL * D_INNER;
    unsigned short* wb_x   = wb_fc + (size_t)VOCAB * D_MODEL;
    unsigned short* wb_dt  = wb_x + (size_t)NLAYERS * XPAD * D_INNER;

    // ---- weight casts ----
    {
        int n4 = NLAYERS * 2 * D_INNER * D_MODEL / 4;
        cast_kernel<<<(n4 + 255) / 256, 256, 0, stream>>>(in_proj, wb_in, n4);
        n4 = NLAYERS * D_MODEL * D_INNER / 4;
        cast_kernel<<<(n4 + 255) / 256, 256, 0, stream>>>(out_proj, wb_out, n4);
        n4 = VOCAB * D_MODEL / 4;
        cast_kernel<<<(n4 + 255) / 256, 256, 0, stream>>>(fc_w, wb_fc, n4);
        n4 = NLAYERS * D_INNER * DT_RANK / 4;
        cast_kernel<<<(n4 + 255) / 256, 256, 0, stream>>>(dt_w, wb_dt, n4);
        n4 = NLAYERS * XPAD * D_INNER / 4;
        cast_pad_xproj<<<(n4 + 255) / 256, 256, 0, stream>>>(x_proj, wb_x);
    }

    // ---- embedding (fp32 + bf16) ----
    gather_kernel<<<M_ROWS, 256, 0, stream>>>(ids, embed, x, xb);

    for (int i = 0; i < NLAYERS; ++i) {
        const unsigned short* W_in_b  = wb_in + (size_t)i * 2 * D_INNER * D_MODEL;
        const unsigned short* W_out_b = wb_out + (size_t)i * D_MODEL * D_INNER;
        const unsigned short* W_x_b   = wb_x + (size_t)i * XPAD * D_INNER;
        const unsigned short* W_dt_b  = wb_dt + (size_t)i * D_INNER * DT_RANK;
        const float* cw    = conv_w + (size_t)i * D_INNER * 4;
        const float* cb    = conv_b + (size_t)i * D_INNER;
        const float* b_dt  = dt_b + (size_t)i * D_INNER;
        const float* Al    = A_log + (size_t)i * D_INNER * D_STATE;
        const float* Dl    = Dp + (size_t)i * D_INNER;
        const float* g     = ln_g + (size_t)i * D_MODEL;
        const float* bb    = ln_b + (size_t)i * D_MODEL;

        // xz = x @ in_proj^T   (2048 x 4096, K=1024)   grid 16x32 = 512
        gemm_bf16_nt<0><<<dim3(M_ROWS / 128, 2 * D_INNER / 128), 256, 0, stream>>>(
            xb, D_MODEL, W_in_b, D_MODEL, xz, 2 * D_INNER, D_MODEL, nullptr, nullptr);

        // xc = silu(conv(xz[:, :2048]) + cb)  (fp32 + bf16)
        conv_silu_kernel<<<(M_ROWS * D_INNER) / 256, 256, 0, stream>>>(xz, cw, cb, xc, xcb);

        // x_dbl = xc @ x_proj_pad^T  (2048 x 128, K=2048)  grid 16x1 = 16
        gemm_bf16_nt<3><<<dim3(M_ROWS / 128, 1), 256, 0, stream>>>(
            xcb, D_INNER, W_x_b, D_INNER, xdbl, XPAD, D_INNER, nullptr, xdbl_b);

        // dt = softplus(x_dbl[:, :64] @ dt_w^T + b_dt)  (2048 x 2048, K=64)  grid 16x16 = 256
        gemm_bf16_nt<1><<<dim3(M_ROWS / 128, D_INNER / 128), 256, 0, stream>>>(
            xdbl_b, XPAD, W_dt_b, DT_RANK, dtbuf, D_INNER, DT_RANK, b_dt, nullptr);

        // chunk-parallel scan -> yb (bf16)
        scan_partial<<<BATCH * NC * (D_INNER / 256), 256, 0, stream>>>(
            dtbuf, xdbl, xc, Al, Hbuf, Pbuf);
        scan_combine<<<(BATCH * D_STATE * D_INNER) / 256, 256, 0, stream>>>(Hbuf, Pbuf);
        scan_final<<<BATCH * NC * (D_INNER / 256), 256, 0, stream>>>(
            dtbuf, xdbl, xc, xz, Al, Dl, Pbuf, yb);

        // tmp = y @ out_proj^T   (2048 x 1024, K=2048)   grid 16x8 = 128
        gemm_bf16_nt<0><<<dim3(M_ROWS / 128, D_MODEL / 128), 256, 0, stream>>>(
            yb, D_INNER, W_out_b, D_INNER, tmp, D_MODEL, D_INNER, nullptr, nullptr);

        // x = LN(tmp + x)  (fp32 + bf16)
        ln_kernel<true><<<M_ROWS, 256, 0, stream>>>(tmp, x, x, xb, g, bb);
    }

    // final LN -> tmp + xb
    ln_kernel<false><<<M_ROWS, 256, 0, stream>>>(nullptr, x, tmp, xb, fn_g, fn_b);

    // logits = xf @ fc_w^T + fc_b   (2048 x 32000, K=1024)   grid 16x250 = 4000
    gemm_bf16_nt<2><<<dim3(M_ROWS / 128, VOCAB / 128), 256, 0, stream>>>(
        xb, D_MODEL, wb_fc, D_MODEL, logits, VOCAB, D_MODEL, fc_b, nullptr);
}

// Round 5
// 1018.907 us; speedup vs baseline: 6.7877x; 1.1540x over previous
//
#include <hip/hip_runtime.h>
#include <cstddef>
#include <cstdint>

#define D_MODEL 1024
#define D_INNER 2048
#define DT_RANK 64
#define D_STATE 8
#define NLAYERS 4
#define BATCH 2
#define SEQ 1024
#define M_ROWS (BATCH*SEQ)   /* 2048 */
#define VOCAB 32000
#define XPAD 128             /* x_proj N padded 80 -> 128 */
#define NC 32                /* scan chunks */
#define LC 32                /* chunk length (NC*LC == SEQ) */
#define XSK 8                /* x_proj split-K factor */

typedef __attribute__((ext_vector_type(8))) short short8;
typedef __attribute__((ext_vector_type(4))) float f32x4;

__device__ __forceinline__ float sigmoidf_(float x) { return 1.f / (1.f + __expf(-x)); }

__device__ __forceinline__ unsigned short f2bf(float f) {
    unsigned u = __float_as_uint(f);
    u += 0x7fffu + ((u >> 16) & 1u);         // round-to-nearest-even
    return (unsigned short)(u >> 16);
}

// ---------------------------------------------------------------------------
// fp32 -> bf16 cast (contiguous), 4 elems/thread.
// ---------------------------------------------------------------------------
__global__ __launch_bounds__(256) void cast_kernel(const float* __restrict__ in,
                                                   unsigned short* __restrict__ out, int n4)
{
    int i = blockIdx.x * 256 + threadIdx.x;
    if (i >= n4) return;
    float4 v = ((const float4*)in)[i];
    ushort4 o;
    o.x = f2bf(v.x); o.y = f2bf(v.y); o.z = f2bf(v.z); o.w = f2bf(v.w);
    ((ushort4*)out)[i] = o;
}

// ---------------------------------------------------------------------------
// x_proj weight: cast 4x(80,2048) fp32 -> 4x(128,2048) bf16, rows 80..127 = 0
// ---------------------------------------------------------------------------
__global__ __launch_bounds__(256) void cast_pad_xproj(const float* __restrict__ in,
                                                      unsigned short* __restrict__ out)
{
    int i = blockIdx.x * 256 + threadIdx.x;     // over 4*128*2048/4 = 262144
    if (i >= NLAYERS * XPAD * D_INNER / 4) return;
    int col4 = i & (D_INNER / 4 - 1);           // 512 col-groups
    int row = (i >> 9) & (XPAD - 1);
    int layer = i >> 16;
    ushort4 o = {0, 0, 0, 0};
    if (row < 80) {
        float4 v = ((const float4*)(in + ((size_t)layer * 80 + row) * D_INNER))[col4];
        o.x = f2bf(v.x); o.y = f2bf(v.y); o.z = f2bf(v.z); o.w = f2bf(v.w);
    }
    ((ushort4*)out)[i] = o;
}

// ---------------------------------------------------------------------------
// Embedding gather -> x (fp32) and xb (bf16)
// ---------------------------------------------------------------------------
__global__ __launch_bounds__(256) void gather_kernel(const int* __restrict__ ids,
                                                     const float* __restrict__ embed,
                                                     float* __restrict__ x,
                                                     unsigned short* __restrict__ xb)
{
    int m = blockIdx.x;
    int t = threadIdx.x;
    int id = ids[m];
    float4 v = ((const float4*)(embed + (size_t)id * D_MODEL))[t];
    ((float4*)(x + (size_t)m * D_MODEL))[t] = v;
    ushort4 o;
    o.x = f2bf(v.x); o.y = f2bf(v.y); o.z = f2bf(v.z); o.w = f2bf(v.w);
    ((ushort4*)(xb + (size_t)m * D_MODEL))[t] = o;
}

// ---------------------------------------------------------------------------
// bf16 MFMA GEMM  C[M,N] = A[M,K] * B[N,K]^T  (fp32 out)
// 128x128 tile, BK=64, 256 thr = 4 waves, XOR-swizzled LDS (conflict-free
// ds_read_b128), linear global_load_lds dest + pre-swizzled global k source.
// blockIdx.z = split-K chunk (K = chunk length); C += z*M_ROWS*ldc for EPI 0.
// Grid x=M/128 (fast), y=N/128; bijective XCD chunk swizzle (nwg%8==0).
// EPI: 0 none | 1 +bias,softplus | 2 +bias
// ---------------------------------------------------------------------------
template<int EPI>
__global__ __launch_bounds__(256) void gemm_bf16_nt(const unsigned short* __restrict__ A, int lda,
                                                    const unsigned short* __restrict__ B, int ldb,
                                                    float* __restrict__ C, int ldc,
                                                    int K, const float* __restrict__ bias)
{
    __shared__ unsigned short As[128 * 64];
    __shared__ unsigned short Bs[128 * 64];
    const int tid = threadIdx.x;

    const int gm = gridDim.x;
    const int bid = blockIdx.y * gm + blockIdx.x;
    const int q = (gm * gridDim.y) >> 3;           // nwg % 8 == 0 guaranteed
    const int swz = (bid & 7) * q + (bid >> 3);
    const int bm = (swz % gm) * 128, bn = (swz / gm) * 128;

    const int wid = tid >> 6, lane = tid & 63;
    const int wm = (wid >> 1) * 64, wn = (wid & 1) * 64;
    const int lrow = lane & 15, lkg = lane >> 4;

    // staging: thread t covers LDS rows {0,32,64,96}+t/8, physical k-unit t%8.
    // Physical slot (row,p) must hold global k-unit p^(row&7)  (T2 swizzle,
    // rule #21: linear LDS dest + inverse-swizzled global source).
    const int srow = tid >> 3;                               // 0..31
    const int ksrc = ((tid & 7) ^ (srow & 7)) * 8;           // elems, const/thread
    const size_t kz = (size_t)blockIdx.z * K;
    const unsigned short* Ag = A + (size_t)(bm + srow) * lda + kz + ksrc;
    const unsigned short* Bg = B + (size_t)(bn + srow) * ldb + kz + ksrc;

    f32x4 acc[4][4];
    #pragma unroll
    for (int i = 0; i < 4; ++i)
        #pragma unroll
        for (int j = 0; j < 4; ++j)
            acc[i][j] = f32x4{0.f, 0.f, 0.f, 0.f};

    for (int k0 = 0; k0 < K; k0 += 64) {
        #pragma unroll
        for (int i = 0; i < 4; ++i) {
            __builtin_amdgcn_global_load_lds(
                (const __attribute__((address_space(1))) void*)(Ag + k0 + (size_t)(32 * i) * lda),
                (__attribute__((address_space(3))) void*)(As + i * 2048 + tid * 8), 16, 0, 0);
            __builtin_amdgcn_global_load_lds(
                (const __attribute__((address_space(1))) void*)(Bg + k0 + (size_t)(32 * i) * ldb),
                (__attribute__((address_space(3))) void*)(Bs + i * 2048 + tid * 8), 16, 0, 0);
        }
        __syncthreads();   // compiler drains vmcnt before barrier -> tiles ready

        #pragma unroll
        for (int kk = 0; kk < 2; ++kk) {
            short8 af[4], bf[4];
            #pragma unroll
            for (int i = 0; i < 4; ++i) {
                int ra = wm + 16 * i + lrow;
                int pa = (kk * 4 + lkg) ^ (ra & 7);
                af[i] = *(const short8*)(As + ra * 64 + pa * 8);
                int rb = wn + 16 * i + lrow;
                int pb = (kk * 4 + lkg) ^ (rb & 7);
                bf[i] = *(const short8*)(Bs + rb * 64 + pb * 8);
            }
            #pragma unroll
            for (int i = 0; i < 4; ++i)
                #pragma unroll
                for (int j = 0; j < 4; ++j)
                    acc[i][j] = __builtin_amdgcn_mfma_f32_16x16x32_bf16(af[i], bf[j], acc[i][j], 0, 0, 0);
        }
        __syncthreads();
    }

    if (gridDim.z > 1) C += (size_t)blockIdx.z * M_ROWS * ldc;

    const int crow = bm + wm + lkg * 4;
    const int ccol = bn + wn + lrow;
    #pragma unroll
    for (int i = 0; i < 4; ++i) {
        #pragma unroll
        for (int j = 0; j < 4; ++j) {
            float bv = (EPI == 1 || EPI == 2) ? bias[ccol + 16 * j] : 0.f;
            float* Cp = C + (size_t)(crow + 16 * i) * ldc + ccol + 16 * j;
            #pragma unroll
            for (int r = 0; r < 4; ++r) {
                float v = acc[i][j][r] + bv;
                if (EPI == 1) v = (v > 20.f) ? v : log1pf(__expf(v));
                Cp[(size_t)r * ldc] = v;
            }
        }
    }
}

// ---------------------------------------------------------------------------
// Reduce XSK split-K partials -> xdbl (fp32) + xdbl_b (bf16)
// ---------------------------------------------------------------------------
__global__ __launch_bounds__(256) void reduce_xdbl(const float* __restrict__ part,
                                                   float* __restrict__ xdbl,
                                                   unsigned short* __restrict__ xdbl_b)
{
    int i = blockIdx.x * 256 + threadIdx.x;     // over 2048*128/4 = 65536
    float4 s = ((const float4*)part)[i];
    #pragma unroll
    for (int z = 1; z < XSK; ++z) {
        float4 v = ((const float4*)part)[(size_t)z * (M_ROWS * XPAD / 4) + i];
        s.x += v.x; s.y += v.y; s.z += v.z; s.w += v.w;
    }
    ((float4*)xdbl)[i] = s;
    ushort4 o;
    o.x = f2bf(s.x); o.y = f2bf(s.y); o.z = f2bf(s.z); o.w = f2bf(s.w);
    ((ushort4*)xdbl_b)[i] = o;
}

// ---------------------------------------------------------------------------
// Causal depthwise conv1d (k=4) + bias + SiLU -> xc (fp32) and xcb (bf16)
// ---------------------------------------------------------------------------
__global__ __launch_bounds__(256) void conv_silu_kernel(const float* __restrict__ xz,
                                                        const float* __restrict__ cw,
                                                        const float* __restrict__ cb,
                                                        float* __restrict__ xc,
                                                        unsigned short* __restrict__ xcb)
{
    int idx = blockIdx.x * 256 + threadIdx.x;
    int d = idx & (D_INNER - 1);
    int m = idx >> 11;
    int l = m & (SEQ - 1);
    int b = m >> 10;
    float w0 = cw[d * 4 + 0], w1 = cw[d * 4 + 1], w2 = cw[d * 4 + 2], w3 = cw[d * 4 + 3];
    float s = cb[d];
    const float* base = xz + ((size_t)b * SEQ) * (2 * D_INNER) + d;
    if (l - 3 >= 0) s += base[(size_t)(l - 3) * (2 * D_INNER)] * w0;
    if (l - 2 >= 0) s += base[(size_t)(l - 2) * (2 * D_INNER)] * w1;
    if (l - 1 >= 0) s += base[(size_t)(l - 1) * (2 * D_INNER)] * w2;
    s += base[(size_t)l * (2 * D_INNER)] * w3;
    float v = s * sigmoidf_(s);
    xc[(size_t)m * D_INNER + d] = v;
    xcb[(size_t)m * D_INNER + d] = f2bf(v);
}

// ---------------------------------------------------------------------------
// Chunk-parallel selective scan (linear recurrence decomposition).
// ---------------------------------------------------------------------------
__global__ __launch_bounds__(256) void scan_partial(const float* __restrict__ dt,
                                                    const float* __restrict__ xdbl,
                                                    const float* __restrict__ xc,
                                                    const float* __restrict__ A_log,
                                                    float* __restrict__ H,
                                                    float* __restrict__ P)
{
    const int tid = threadIdx.x;
    const int b = blockIdx.x & 1;
    const int c = (blockIdx.x >> 1) & (NC - 1);
    const int d = ((blockIdx.x >> 6) << 8) + tid;

    __shared__ float Bs[LC][8];
    {
        int r = tid >> 3, n = tid & 7;
        Bs[r][n] = xdbl[(size_t)(b * SEQ + c * LC + r) * XPAD + DT_RANK + n];
    }
    __syncthreads();

    float An[8];
    #pragma unroll
    for (int n = 0; n < 8; ++n) An[n] = -__expf(A_log[d * 8 + n]);
    float h[8] = {0.f,0.f,0.f,0.f,0.f,0.f,0.f,0.f};
    float p[8] = {1.f,1.f,1.f,1.f,1.f,1.f,1.f,1.f};

    const float* dtp = dt + (size_t)(b * SEQ + c * LC) * D_INNER + d;
    const float* xcp = xc + (size_t)(b * SEQ + c * LC) * D_INNER + d;
    for (int l = 0; l < LC; ++l) {
        float dtv = dtp[(size_t)l * D_INNER];
        float ux  = dtv * xcp[(size_t)l * D_INNER];
        #pragma unroll
        for (int n = 0; n < 8; ++n) {
            float dA = __expf(dtv * An[n]);
            h[n] = dA * h[n] + Bs[l][n] * ux;
            p[n] *= dA;
        }
    }
    size_t base = (size_t)((b * NC + c) * 8) * D_INNER + d;
    #pragma unroll
    for (int n = 0; n < 8; ++n) {
        H[base + (size_t)n * D_INNER] = h[n];
        P[base + (size_t)n * D_INNER] = p[n];
    }
}

__global__ __launch_bounds__(256) void scan_combine(const float* __restrict__ H,
                                                    float* __restrict__ P /* -> h0 */)
{
    int idx = blockIdx.x * 256 + threadIdx.x;   // 32768 = 2*8*2048
    int d = idx & (D_INNER - 1);
    int n = (idx >> 11) & 7;
    int b = idx >> 14;
    float hp = 0.f;
    for (int c = 0; c < NC; ++c) {
        size_t base = (size_t)((b * NC + c) * 8 + n) * D_INNER + d;
        float Pv = P[base], Hv = H[base];
        P[base] = hp;
        hp = Pv * hp + Hv;
    }
}

__global__ __launch_bounds__(256) void scan_final(const float* __restrict__ dt,
                                                  const float* __restrict__ xdbl,
                                                  const float* __restrict__ xc,
                                                  const float* __restrict__ xz,
                                                  const float* __restrict__ A_log,
                                                  const float* __restrict__ Dp,
                                                  const float* __restrict__ h0,
                                                  unsigned short* __restrict__ yb)
{
    const int tid = threadIdx.x;
    const int b = blockIdx.x & 1;
    const int c = (blockIdx.x >> 1) & (NC - 1);
    const int d = ((blockIdx.x >> 6) << 8) + tid;

    __shared__ float Bs[LC][8];
    __shared__ float Cs[LC][8];
    {
        int r = tid >> 3, n = tid & 7;
        size_t xrow = (size_t)(b * SEQ + c * LC + r) * XPAD;
        Bs[r][n] = xdbl[xrow + DT_RANK + n];
        Cs[r][n] = xdbl[xrow + DT_RANK + 8 + n];
    }
    __syncthreads();

    float An[8], h[8];
    size_t base = (size_t)((b * NC + c) * 8) * D_INNER + d;
    #pragma unroll
    for (int n = 0; n < 8; ++n) {
        An[n] = -__expf(A_log[d * 8 + n]);
        h[n] = h0[base + (size_t)n * D_INNER];
    }
    const float Dv = Dp[d];

    const float* dtp = dt + (size_t)(b * SEQ + c * LC) * D_INNER + d;
    const float* xcp = xc + (size_t)(b * SEQ + c * LC) * D_INNER + d;
    const float* zp  = xz + (size_t)(b * SEQ + c * LC) * (2 * D_INNER) + D_INNER + d;
    unsigned short* ybp = yb + (size_t)(b * SEQ + c * LC) * D_INNER + d;

    for (int l = 0; l < LC; ++l) {
        float dtv = dtp[(size_t)l * D_INNER];
        float xcv = xcp[(size_t)l * D_INNER];
        float zv  = zp[(size_t)l * (2 * D_INNER)];
        float ux = dtv * xcv;
        float acc = 0.f;
        #pragma unroll
        for (int n = 0; n < 8; ++n) {
            float dA = __expf(dtv * An[n]);
            h[n] = dA * h[n] + Bs[l][n] * ux;
            acc += h[n] * Cs[l][n];
        }
        float yv = (acc + xcv * Dv) * (zv * sigmoidf_(zv));
        ybp[(size_t)l * D_INNER] = f2bf(yv);
    }
}

// ---------------------------------------------------------------------------
// LayerNorm (1024). ADD: out = LN(extra + xin) else LN(xin). Emits fp32 + bf16.
// ---------------------------------------------------------------------------
template<bool ADD>
__global__ __launch_bounds__(256) void ln_kernel(const float* __restrict__ extra,
                                                 const float* __restrict__ xin,
                                                 float* __restrict__ xout,
                                                 unsigned short* __restrict__ xbout,
                                                 const float* __restrict__ g,
                                                 const float* __restrict__ bb)
{
    int m = blockIdx.x;
    int t = threadIdx.x;
    float4 v = ((const float4*)(xin + (size_t)m * D_MODEL))[t];
    if (ADD) {
        float4 e = ((const float4*)(extra + (size_t)m * D_MODEL))[t];
        v.x += e.x; v.y += e.y; v.z += e.z; v.w += e.w;
    }
    float s  = v.x + v.y + v.z + v.w;
    float s2 = v.x * v.x + v.y * v.y + v.z * v.z + v.w * v.w;
    for (int off = 32; off; off >>= 1) {
        s  += __shfl_down(s, off);
        s2 += __shfl_down(s2, off);
    }
    __shared__ float red[8];
    int wid = t >> 6, lane = t & 63;
    if (lane == 0) { red[wid] = s; red[wid + 4] = s2; }
    __syncthreads();
    if (t == 0) {
        float a  = red[0] + red[1] + red[2] + red[3];
        float b2 = red[4] + red[5] + red[6] + red[7];
        float mu = a * (1.f / D_MODEL);
        red[0] = mu;
        red[4] = b2 * (1.f / D_MODEL) - mu * mu;
    }
    __syncthreads();
    float mu = red[0];
    float rs = rsqrtf(red[4] + 1e-5f);
    float4 gg = ((const float4*)g)[t];
    float4 bv = ((const float4*)bb)[t];
    float4 o;
    o.x = (v.x - mu) * rs * gg.x + bv.x;
    o.y = (v.y - mu) * rs * gg.y + bv.y;
    o.z = (v.z - mu) * rs * gg.z + bv.z;
    o.w = (v.w - mu) * rs * gg.w + bv.w;
    ((float4*)(xout + (size_t)m * D_MODEL))[t] = o;
    ushort4 ob;
    ob.x = f2bf(o.x); ob.y = f2bf(o.y); ob.z = f2bf(o.z); ob.w = f2bf(o.w);
    ((ushort4*)(xbout + (size_t)m * D_MODEL))[t] = ob;
}

// ---------------------------------------------------------------------------
extern "C" void kernel_launch(void* const* d_in, const int* in_sizes, int n_in,
                              void* d_out, int out_size, void* d_ws, size_t ws_size,
                              hipStream_t stream)
{
    const int*   ids      = (const int*)d_in[0];
    const float* embed    = (const float*)d_in[1];
    const float* in_proj  = (const float*)d_in[2];
    const float* conv_w   = (const float*)d_in[3];
    const float* conv_b   = (const float*)d_in[4];
    const float* x_proj   = (const float*)d_in[5];
    const float* dt_w     = (const float*)d_in[6];
    const float* dt_b     = (const float*)d_in[7];
    const float* A_log    = (const float*)d_in[8];
    const float* Dp       = (const float*)d_in[9];
    const float* out_proj = (const float*)d_in[10];
    const float* ln_g     = (const float*)d_in[11];
    const float* ln_b     = (const float*)d_in[12];
    const float* fn_g     = (const float*)d_in[13];
    const float* fn_b     = (const float*)d_in[14];
    const float* fc_w     = (const float*)d_in[15];
    const float* fc_b     = (const float*)d_in[16];
    float* logits = (float*)d_out;

    // ---- workspace layout ----
    float* ws = (float*)d_ws;
    float* x     = ws;                                   // 2048*1024
    float* xz    = x + (size_t)M_ROWS * D_MODEL;         // 2048*4096
    float* xc    = xz + (size_t)M_ROWS * 2 * D_INNER;    // 2048*2048
    float* xdbl  = xc + (size_t)M_ROWS * D_INNER;        // 2048*128
    float* dtbuf = xdbl + (size_t)M_ROWS * XPAD;         // 2048*2048
    float* tmp   = dtbuf + (size_t)M_ROWS * D_INNER;     // 2048*1024
    float* xpart = tmp + (size_t)M_ROWS * D_MODEL;       // XSK*2048*128

    float* Hbuf = tmp;
    float* Pbuf = tmp + (size_t)BATCH * NC * D_STATE * D_INNER;

    unsigned short* xb     = (unsigned short*)(xpart + (size_t)XSK * M_ROWS * XPAD);
    unsigned short* yb     = xb + (size_t)M_ROWS * D_MODEL;
    unsigned short* xcb    = yb + (size_t)M_ROWS * D_INNER;
    unsigned short* xdbl_b = xcb + (size_t)M_ROWS * D_INNER;
    unsigned short* wb_in  = xdbl_b + (size_t)M_ROWS * XPAD;
    unsigned short* wb_out = wb_in + (size_t)NLAYERS * 2 * D_INNER * D_MODEL;
    unsigned short* wb_fc  = wb_out + (size_t)NLAYERS * D_MODEL * D_INNER;
    unsigned short* wb_x   = wb_fc + (size_t)VOCAB * D_MODEL;
    unsigned short* wb_dt  = wb_x + (size_t)NLAYERS * XPAD * D_INNER;

    // ---- weight casts ----
    {
        int n4 = NLAYERS * 2 * D_INNER * D_MODEL / 4;
        cast_kernel<<<(n4 + 255) / 256, 256, 0, stream>>>(in_proj, wb_in, n4);
        n4 = NLAYERS * D_MODEL * D_INNER / 4;
        cast_kernel<<<(n4 + 255) / 256, 256, 0, stream>>>(out_proj, wb_out, n4);
        n4 = VOCAB * D_MODEL / 4;
        cast_kernel<<<(n4 + 255) / 256, 256, 0, stream>>>(fc_w, wb_fc, n4);
        n4 = NLAYERS * D_INNER * DT_RANK / 4;
        cast_kernel<<<(n4 + 255) / 256, 256, 0, stream>>>(dt_w, wb_dt, n4);
        n4 = NLAYERS * XPAD * D_INNER / 4;
        cast_pad_xproj<<<(n4 + 255) / 256, 256, 0, stream>>>(x_proj, wb_x);
    }

    // ---- embedding (fp32 + bf16) ----
    gather_kernel<<<M_ROWS, 256, 0, stream>>>(ids, embed, x, xb);

    for (int i = 0; i < NLAYERS; ++i) {
        const unsigned short* W_in_b  = wb_in + (size_t)i * 2 * D_INNER * D_MODEL;
        const unsigned short* W_out_b = wb_out + (size_t)i * D_MODEL * D_INNER;
        const unsigned short* W_x_b   = wb_x + (size_t)i * XPAD * D_INNER;
        const unsigned short* W_dt_b  = wb_dt + (size_t)i * D_INNER * DT_RANK;
        const float* cw    = conv_w + (size_t)i * D_INNER * 4;
        const float* cb    = conv_b + (size_t)i * D_INNER;
        const float* b_dt  = dt_b + (size_t)i * D_INNER;
        const float* Al    = A_log + (size_t)i * D_INNER * D_STATE;
        const float* Dl    = Dp + (size_t)i * D_INNER;
        const float* g     = ln_g + (size_t)i * D_MODEL;
        const float* bb    = ln_b + (size_t)i * D_MODEL;

        // xz = x @ in_proj^T   (2048 x 4096, K=1024)   grid 16x32
        gemm_bf16_nt<0><<<dim3(M_ROWS / 128, 2 * D_INNER / 128), 256, 0, stream>>>(
            xb, D_MODEL, W_in_b, D_MODEL, xz, 2 * D_INNER, D_MODEL, nullptr);

        // xc = silu(conv(xz[:, :2048]) + cb)  (fp32 + bf16)
        conv_silu_kernel<<<(M_ROWS * D_INNER) / 256, 256, 0, stream>>>(xz, cw, cb, xc, xcb);

        // x_dbl partials: (2048 x 128, K=2048 split XSK x 256)  grid 16x1x8
        gemm_bf16_nt<0><<<dim3(M_ROWS / 128, 1, XSK), 256, 0, stream>>>(
            xcb, D_INNER, W_x_b, D_INNER, xpart, XPAD, D_INNER / XSK, nullptr);
        reduce_xdbl<<<(M_ROWS * XPAD / 4) / 256, 256, 0, stream>>>(xpart, xdbl, xdbl_b);

        // dt = softplus(x_dbl[:, :64] @ dt_w^T + b_dt)  (2048 x 2048, K=64)  grid 16x16
        gemm_bf16_nt<1><<<dim3(M_ROWS / 128, D_INNER / 128), 256, 0, stream>>>(
            xdbl_b, XPAD, W_dt_b, DT_RANK, dtbuf, D_INNER, DT_RANK, b_dt);

        // chunk-parallel scan -> yb (bf16)
        scan_partial<<<BATCH * NC * (D_INNER / 256), 256, 0, stream>>>(
            dtbuf, xdbl, xc, Al, Hbuf, Pbuf);
        scan_combine<<<(BATCH * D_STATE * D_INNER) / 256, 256, 0, stream>>>(Hbuf, Pbuf);
        scan_final<<<BATCH * NC * (D_INNER / 256), 256, 0, stream>>>(
            dtbuf, xdbl, xc, xz, Al, Dl, Pbuf, yb);

        // tmp = y @ out_proj^T   (2048 x 1024, K=2048)   grid 16x8
        gemm_bf16_nt<0><<<dim3(M_ROWS / 128, D_MODEL / 128), 256, 0, stream>>>(
            yb, D_INNER, W_out_b, D_INNER, tmp, D_MODEL, D_INNER, nullptr);

        // x = LN(tmp + x)  (fp32 + bf16)
        ln_kernel<true><<<M_ROWS, 256, 0, stream>>>(tmp, x, x, xb, g, bb);
    }

    // final LN -> tmp + xb
    ln_kernel<false><<<M_ROWS, 256, 0, stream>>>(nullptr, x, tmp, xb, fn_g, fn_b);

    // logits = xf @ fc_w^T + fc_b   (2048 x 32000, K=1024)   grid 16x250
    gemm_bf16_nt<2><<<dim3(M_ROWS / 128, VOCAB / 128), 256, 0, stream>>>(
        xb, D_MODEL, wb_fc, D_MODEL, logits, VOCAB, D_MODEL, fc_b);
}

// Round 6
// 1017.408 us; speedup vs baseline: 6.7977x; 1.0015x over previous
//
#include <hip/hip_runtime.h>
#include <cstddef>
#include <cstdint>

#define D_MODEL 1024
#define D_INNER 2048
#define DT_RANK 64
#define D_STATE 8
#define NLAYERS 4
#define BATCH 2
#define SEQ 1024
#define M_ROWS (BATCH*SEQ)   /* 2048 */
#define VOCAB 32000
#define XPAD 128             /* x_proj N padded 80 -> 128 */
#define NC 32                /* scan chunks */
#define LC 32                /* chunk length (NC*LC == SEQ) */
#define XSK 8                /* x_proj split-K factor */

typedef __attribute__((ext_vector_type(8))) short short8;
typedef __attribute__((ext_vector_type(4))) float f32x4;

#define GPTR(p) (const __attribute__((address_space(1))) void*)(p)
#define LPTR(p) (__attribute__((address_space(3))) void*)(p)

__device__ __forceinline__ float sigmoidf_(float x) { return 1.f / (1.f + __expf(-x)); }

__device__ __forceinline__ unsigned short f2bf(float f) {
    unsigned u = __float_as_uint(f);
    u += 0x7fffu + ((u >> 16) & 1u);         // round-to-nearest-even
    return (unsigned short)(u >> 16);
}

// ---------------------------------------------------------------------------
// fp32 -> bf16 cast (contiguous), 4 elems/thread.
// ---------------------------------------------------------------------------
__global__ __launch_bounds__(256) void cast_kernel(const float* __restrict__ in,
                                                   unsigned short* __restrict__ out, int n4)
{
    int i = blockIdx.x * 256 + threadIdx.x;
    if (i >= n4) return;
    float4 v = ((const float4*)in)[i];
    ushort4 o;
    o.x = f2bf(v.x); o.y = f2bf(v.y); o.z = f2bf(v.z); o.w = f2bf(v.w);
    ((ushort4*)out)[i] = o;
}

// ---------------------------------------------------------------------------
// x_proj weight: cast 4x(80,2048) fp32 -> 4x(128,2048) bf16, rows 80..127 = 0
// ---------------------------------------------------------------------------
__global__ __launch_bounds__(256) void cast_pad_xproj(const float* __restrict__ in,
                                                      unsigned short* __restrict__ out)
{
    int i = blockIdx.x * 256 + threadIdx.x;     // over 4*128*2048/4 = 262144
    if (i >= NLAYERS * XPAD * D_INNER / 4) return;
    int col4 = i & (D_INNER / 4 - 1);           // 512 col-groups
    int row = (i >> 9) & (XPAD - 1);
    int layer = i >> 16;
    ushort4 o = {0, 0, 0, 0};
    if (row < 80) {
        float4 v = ((const float4*)(in + ((size_t)layer * 80 + row) * D_INNER))[col4];
        o.x = f2bf(v.x); o.y = f2bf(v.y); o.z = f2bf(v.z); o.w = f2bf(v.w);
    }
    ((ushort4*)out)[i] = o;
}

// ---------------------------------------------------------------------------
// Embedding gather -> x (fp32) and xb (bf16)
// ---------------------------------------------------------------------------
__global__ __launch_bounds__(256) void gather_kernel(const int* __restrict__ ids,
                                                     const float* __restrict__ embed,
                                                     float* __restrict__ x,
                                                     unsigned short* __restrict__ xb)
{
    int m = blockIdx.x;
    int t = threadIdx.x;
    int id = ids[m];
    float4 v = ((const float4*)(embed + (size_t)id * D_MODEL))[t];
    ((float4*)(x + (size_t)m * D_MODEL))[t] = v;
    ushort4 o;
    o.x = f2bf(v.x); o.y = f2bf(v.y); o.z = f2bf(v.z); o.w = f2bf(v.w);
    ((ushort4*)(xb + (size_t)m * D_MODEL))[t] = o;
}

// ---------------------------------------------------------------------------
// bf16 MFMA GEMM  C[M,N] = A[M,K] * B[N,K]^T  (fp32 out)
// 128x128 tile, BK=32, 256 thr = 4 waves. Double-buffered LDS, 2-phase
// prefetch pipeline (T3-minimum): STAGE(next) issued BEFORE compute(cur),
// ONE barrier per K-step (drain happens after MFMA covers the latency).
// T2 LDS swizzle: 16B unit p = u ^ ((row>>1)&3); linear global_load_lds dest
// + inverse-swizzled global k source (rule #21).
// blockIdx.z = split-K chunk (K = chunk length); C += z*M_ROWS*ldc.
// Grid x=M/128 (fast), y=N/128; bijective XCD chunk swizzle (x*y % 8 == 0).
// EPI: 0 none | 1 +bias,softplus | 2 +bias
// ---------------------------------------------------------------------------
template<int EPI>
__global__ __launch_bounds__(256) void gemm_bf16_nt(const unsigned short* __restrict__ A, int lda,
                                                    const unsigned short* __restrict__ B, int ldb,
                                                    float* __restrict__ C, int ldc,
                                                    int K, const float* __restrict__ bias)
{
    __shared__ unsigned short As[2][128 * 32];
    __shared__ unsigned short Bs[2][128 * 32];
    const int tid = threadIdx.x;

    const int gm = gridDim.x;
    const int bid = blockIdx.y * gm + blockIdx.x;
    const int q = (gm * gridDim.y) >> 3;           // nwg % 8 == 0 guaranteed
    const int swz = (bid & 7) * q + (bid >> 3);
    const int bm = (swz % gm) * 128, bn = (swz / gm) * 128;

    const int wid = tid >> 6, lane = tid & 63;
    const int wm = (wid >> 1) * 64, wn = (wid & 1) * 64;
    const int lrow = lane & 15, lkg = lane >> 4;

    // staging: load j covers LDS elems [j*2048 + tid*8, +8)
    //   -> row = 64j + (tid>>2), phys 16B-unit p = tid&3
    //   slot (row,p) must hold global k-unit p ^ ((row>>1)&3)
    const int srow = tid >> 2;                               // 0..63
    const int ksrc = ((tid & 3) ^ ((srow >> 1) & 3)) * 8;    // elems, const/thread
    const size_t kz = (size_t)blockIdx.z * K;
    const unsigned short* Ag = A + (size_t)(bm + srow) * lda + kz + ksrc;
    const unsigned short* Bg = B + (size_t)(bn + srow) * ldb + kz + ksrc;
    const size_t r64a = (size_t)64 * lda;
    const size_t r64b = (size_t)64 * ldb;

#define STAGE(buf, koff)                                                                              \
    do {                                                                                              \
        __builtin_amdgcn_global_load_lds(GPTR(Ag + (koff)),        LPTR(&As[buf][tid * 8]), 16, 0, 0);\
        __builtin_amdgcn_global_load_lds(GPTR(Ag + r64a + (koff)), LPTR(&As[buf][2048 + tid * 8]), 16, 0, 0);\
        __builtin_amdgcn_global_load_lds(GPTR(Bg + (koff)),        LPTR(&Bs[buf][tid * 8]), 16, 0, 0);\
        __builtin_amdgcn_global_load_lds(GPTR(Bg + r64b + (koff)), LPTR(&Bs[buf][2048 + tid * 8]), 16, 0, 0);\
    } while (0)

    f32x4 acc[4][4];
    #pragma unroll
    for (int i = 0; i < 4; ++i)
        #pragma unroll
        for (int j = 0; j < 4; ++j)
            acc[i][j] = f32x4{0.f, 0.f, 0.f, 0.f};

    // prologue: stage first tile
    STAGE(0, 0);
    __syncthreads();

    int cur = 0;
    // read-side swizzle: u = lkg, row parity bits -> p = lkg ^ ((row>>1)&3);
    // wm/wn/16i are multiples of 16, so (row>>1)&3 = ((lrow>>1)&3) ^ (8i>>... )
    for (int k0 = 0; k0 < K; k0 += 32) {
        if (k0 + 32 < K) STAGE(cur ^ 1, k0 + 32);   // issue next-tile loads EARLY

        short8 af[4], bf[4];
        #pragma unroll
        for (int i = 0; i < 4; ++i) {
            int ra = wm + 16 * i + lrow;
            int pa = lkg ^ ((ra >> 1) & 3);
            af[i] = *(const short8*)(&As[cur][ra * 32 + pa * 8]);
            int rb = wn + 16 * i + lrow;
            int pb = lkg ^ ((rb >> 1) & 3);
            bf[i] = *(const short8*)(&Bs[cur][rb * 32 + pb * 8]);
        }
        #pragma unroll
        for (int i = 0; i < 4; ++i)
            #pragma unroll
            for (int j = 0; j < 4; ++j)
                acc[i][j] = __builtin_amdgcn_mfma_f32_16x16x32_bf16(af[i], bf[j], acc[i][j], 0, 0, 0);

        __syncthreads();   // drains vmcnt(0): next tile staged; all reads of cur done
        cur ^= 1;
    }
#undef STAGE

    if (gridDim.z > 1) C += (size_t)blockIdx.z * M_ROWS * ldc;

    const int crow = bm + wm + lkg * 4;
    const int ccol = bn + wn + lrow;
    #pragma unroll
    for (int i = 0; i < 4; ++i) {
        #pragma unroll
        for (int j = 0; j < 4; ++j) {
            float bv = (EPI == 1 || EPI == 2) ? bias[ccol + 16 * j] : 0.f;
            float* Cp = C + (size_t)(crow + 16 * i) * ldc + ccol + 16 * j;
            #pragma unroll
            for (int r = 0; r < 4; ++r) {
                float v = acc[i][j][r] + bv;
                if (EPI == 1) v = (v > 20.f) ? v : log1pf(__expf(v));
                Cp[(size_t)r * ldc] = v;
            }
        }
    }
}

// ---------------------------------------------------------------------------
// Reduce XSK split-K partials -> xdbl (fp32) + xdbl_b (bf16)
// ---------------------------------------------------------------------------
__global__ __launch_bounds__(256) void reduce_xdbl(const float* __restrict__ part,
                                                   float* __restrict__ xdbl,
                                                   unsigned short* __restrict__ xdbl_b)
{
    int i = blockIdx.x * 256 + threadIdx.x;     // over 2048*128/4 = 65536
    float4 s = ((const float4*)part)[i];
    #pragma unroll
    for (int z = 1; z < XSK; ++z) {
        float4 v = ((const float4*)part)[(size_t)z * (M_ROWS * XPAD / 4) + i];
        s.x += v.x; s.y += v.y; s.z += v.z; s.w += v.w;
    }
    ((float4*)xdbl)[i] = s;
    ushort4 o;
    o.x = f2bf(s.x); o.y = f2bf(s.y); o.z = f2bf(s.z); o.w = f2bf(s.w);
    ((ushort4*)xdbl_b)[i] = o;
}

// ---------------------------------------------------------------------------
// Causal depthwise conv1d (k=4) + bias + SiLU -> xc (fp32) and xcb (bf16)
// ---------------------------------------------------------------------------
__global__ __launch_bounds__(256) void conv_silu_kernel(const float* __restrict__ xz,
                                                        const float* __restrict__ cw,
                                                        const float* __restrict__ cb,
                                                        float* __restrict__ xc,
                                                        unsigned short* __restrict__ xcb)
{
    int idx = blockIdx.x * 256 + threadIdx.x;
    int d = idx & (D_INNER - 1);
    int m = idx >> 11;
    int l = m & (SEQ - 1);
    int b = m >> 10;
    float w0 = cw[d * 4 + 0], w1 = cw[d * 4 + 1], w2 = cw[d * 4 + 2], w3 = cw[d * 4 + 3];
    float s = cb[d];
    const float* base = xz + ((size_t)b * SEQ) * (2 * D_INNER) + d;
    if (l - 3 >= 0) s += base[(size_t)(l - 3) * (2 * D_INNER)] * w0;
    if (l - 2 >= 0) s += base[(size_t)(l - 2) * (2 * D_INNER)] * w1;
    if (l - 1 >= 0) s += base[(size_t)(l - 1) * (2 * D_INNER)] * w2;
    s += base[(size_t)l * (2 * D_INNER)] * w3;
    float v = s * sigmoidf_(s);
    xc[(size_t)m * D_INNER + d] = v;
    xcb[(size_t)m * D_INNER + d] = f2bf(v);
}

// ---------------------------------------------------------------------------
// Chunk-parallel selective scan (linear recurrence decomposition).
// ---------------------------------------------------------------------------
__global__ __launch_bounds__(256) void scan_partial(const float* __restrict__ dt,
                                                    const float* __restrict__ xdbl,
                                                    const float* __restrict__ xc,
                                                    const float* __restrict__ A_log,
                                                    float* __restrict__ H,
                                                    float* __restrict__ P)
{
    const int tid = threadIdx.x;
    const int b = blockIdx.x & 1;
    const int c = (blockIdx.x >> 1) & (NC - 1);
    const int d = ((blockIdx.x >> 6) << 8) + tid;

    __shared__ float Bs[LC][8];
    {
        int r = tid >> 3, n = tid & 7;
        Bs[r][n] = xdbl[(size_t)(b * SEQ + c * LC + r) * XPAD + DT_RANK + n];
    }
    __syncthreads();

    float An[8];
    #pragma unroll
    for (int n = 0; n < 8; ++n) An[n] = -__expf(A_log[d * 8 + n]);
    float h[8] = {0.f,0.f,0.f,0.f,0.f,0.f,0.f,0.f};
    float p[8] = {1.f,1.f,1.f,1.f,1.f,1.f,1.f,1.f};

    const float* dtp = dt + (size_t)(b * SEQ + c * LC) * D_INNER + d;
    const float* xcp = xc + (size_t)(b * SEQ + c * LC) * D_INNER + d;
    for (int l = 0; l < LC; ++l) {
        float dtv = dtp[(size_t)l * D_INNER];
        float ux  = dtv * xcp[(size_t)l * D_INNER];
        #pragma unroll
        for (int n = 0; n < 8; ++n) {
            float dA = __expf(dtv * An[n]);
            h[n] = dA * h[n] + Bs[l][n] * ux;
            p[n] *= dA;
        }
    }
    size_t base = (size_t)((b * NC + c) * 8) * D_INNER + d;
    #pragma unroll
    for (int n = 0; n < 8; ++n) {
        H[base + (size_t)n * D_INNER] = h[n];
        P[base + (size_t)n * D_INNER] = p[n];
    }
}

__global__ __launch_bounds__(256) void scan_combine(const float* __restrict__ H,
                                                    float* __restrict__ P /* -> h0 */)
{
    int idx = blockIdx.x * 256 + threadIdx.x;   // 32768 = 2*8*2048
    int d = idx & (D_INNER - 1);
    int n = (idx >> 11) & 7;
    int b = idx >> 14;
    float hp = 0.f;
    for (int c = 0; c < NC; ++c) {
        size_t base = (size_t)((b * NC + c) * 8 + n) * D_INNER + d;
        float Pv = P[base], Hv = H[base];
        P[base] = hp;
        hp = Pv * hp + Hv;
    }
}

__global__ __launch_bounds__(256) void scan_final(const float* __restrict__ dt,
                                                  const float* __restrict__ xdbl,
                                                  const float* __restrict__ xc,
                                                  const float* __restrict__ xz,
                                                  const float* __restrict__ A_log,
                                                  const float* __restrict__ Dp,
                                                  const float* __restrict__ h0,
                                                  unsigned short* __restrict__ yb)
{
    const int tid = threadIdx.x;
    const int b = blockIdx.x & 1;
    const int c = (blockIdx.x >> 1) & (NC - 1);
    const int d = ((blockIdx.x >> 6) << 8) + tid;

    __shared__ float Bs[LC][8];
    __shared__ float Cs[LC][8];
    {
        int r = tid >> 3, n = tid & 7;
        size_t xrow = (size_t)(b * SEQ + c * LC + r) * XPAD;
        Bs[r][n] = xdbl[xrow + DT_RANK + n];
        Cs[r][n] = xdbl[xrow + DT_RANK + 8 + n];
    }
    __syncthreads();

    float An[8], h[8];
    size_t base = (size_t)((b * NC + c) * 8) * D_INNER + d;
    #pragma unroll
    for (int n = 0; n < 8; ++n) {
        An[n] = -__expf(A_log[d * 8 + n]);
        h[n] = h0[base + (size_t)n * D_INNER];
    }
    const float Dv = Dp[d];

    const float* dtp = dt + (size_t)(b * SEQ + c * LC) * D_INNER + d;
    const float* xcp = xc + (size_t)(b * SEQ + c * LC) * D_INNER + d;
    const float* zp  = xz + (size_t)(b * SEQ + c * LC) * (2 * D_INNER) + D_INNER + d;
    unsigned short* ybp = yb + (size_t)(b * SEQ + c * LC) * D_INNER + d;

    for (int l = 0; l < LC; ++l) {
        float dtv = dtp[(size_t)l * D_INNER];
        float xcv = xcp[(size_t)l * D_INNER];
        float zv  = zp[(size_t)l * (2 * D_INNER)];
        float ux = dtv * xcv;
        float acc = 0.f;
        #pragma unroll
        for (int n = 0; n < 8; ++n) {
            float dA = __expf(dtv * An[n]);
            h[n] = dA * h[n] + Bs[l][n] * ux;
            acc += h[n] * Cs[l][n];
        }
        float yv = (acc + xcv * Dv) * (zv * sigmoidf_(zv));
        ybp[(size_t)l * D_INNER] = f2bf(yv);
    }
}

// ---------------------------------------------------------------------------
// LayerNorm (1024). ADD: out = LN(extra + xin) else LN(xin). Emits fp32 + bf16.
// ---------------------------------------------------------------------------
template<bool ADD>
__global__ __launch_bounds__(256) void ln_kernel(const float* __restrict__ extra,
                                                 const float* __restrict__ xin,
                                                 float* __restrict__ xout,
                                                 unsigned short* __restrict__ xbout,
                                                 const float* __restrict__ g,
                                                 const float* __restrict__ bb)
{
    int m = blockIdx.x;
    int t = threadIdx.x;
    float4 v = ((const float4*)(xin + (size_t)m * D_MODEL))[t];
    if (ADD) {
        float4 e = ((const float4*)(extra + (size_t)m * D_MODEL))[t];
        v.x += e.x; v.y += e.y; v.z += e.z; v.w += e.w;
    }
    float s  = v.x + v.y + v.z + v.w;
    float s2 = v.x * v.x + v.y * v.y + v.z * v.z + v.w * v.w;
    for (int off = 32; off; off >>= 1) {
        s  += __shfl_down(s, off);
        s2 += __shfl_down(s2, off);
    }
    __shared__ float red[8];
    int wid = t >> 6, lane = t & 63;
    if (lane == 0) { red[wid] = s; red[wid + 4] = s2; }
    __syncthreads();
    if (t == 0) {
        float a  = red[0] + red[1] + red[2] + red[3];
        float b2 = red[4] + red[5] + red[6] + red[7];
        float mu = a * (1.f / D_MODEL);
        red[0] = mu;
        red[4] = b2 * (1.f / D_MODEL) - mu * mu;
    }
    __syncthreads();
    float mu = red[0];
    float rs = rsqrtf(red[4] + 1e-5f);
    float4 gg = ((const float4*)g)[t];
    float4 bv = ((const float4*)bb)[t];
    float4 o;
    o.x = (v.x - mu) * rs * gg.x + bv.x;
    o.y = (v.y - mu) * rs * gg.y + bv.y;
    o.z = (v.z - mu) * rs * gg.z + bv.z;
    o.w = (v.w - mu) * rs * gg.w + bv.w;
    ((float4*)(xout + (size_t)m * D_MODEL))[t] = o;
    ushort4 ob;
    ob.x = f2bf(o.x); ob.y = f2bf(o.y); ob.z = f2bf(o.z); ob.w = f2bf(o.w);
    ((ushort4*)(xbout + (size_t)m * D_MODEL))[t] = ob;
}

// ---------------------------------------------------------------------------
extern "C" void kernel_launch(void* const* d_in, const int* in_sizes, int n_in,
                              void* d_out, int out_size, void* d_ws, size_t ws_size,
                              hipStream_t stream)
{
    const int*   ids      = (const int*)d_in[0];
    const float* embed    = (const float*)d_in[1];
    const float* in_proj  = (const float*)d_in[2];
    const float* conv_w   = (const float*)d_in[3];
    const float* conv_b   = (const float*)d_in[4];
    const float* x_proj   = (const float*)d_in[5];
    const float* dt_w     = (const float*)d_in[6];
    const float* dt_b     = (const float*)d_in[7];
    const float* A_log    = (const float*)d_in[8];
    const float* Dp       = (const float*)d_in[9];
    const float* out_proj = (const float*)d_in[10];
    const float* ln_g     = (const float*)d_in[11];
    const float* ln_b     = (const float*)d_in[12];
    const float* fn_g     = (const float*)d_in[13];
    const float* fn_b     = (const float*)d_in[14];
    const float* fc_w     = (const float*)d_in[15];
    const float* fc_b     = (const float*)d_in[16];
    float* logits = (float*)d_out;

    // ---- workspace layout ----
    float* ws = (float*)d_ws;
    float* x     = ws;                                   // 2048*1024
    float* xz    = x + (size_t)M_ROWS * D_MODEL;         // 2048*4096
    float* xc    = xz + (size_t)M_ROWS * 2 * D_INNER;    // 2048*2048
    float* xdbl  = xc + (size_t)M_ROWS * D_INNER;        // 2048*128
    float* dtbuf = xdbl + (size_t)M_ROWS * XPAD;         // 2048*2048
    float* tmp   = dtbuf + (size_t)M_ROWS * D_INNER;     // 2048*1024
    float* xpart = tmp + (size_t)M_ROWS * D_MODEL;       // XSK*2048*128

    float* Hbuf = tmp;
    float* Pbuf = tmp + (size_t)BATCH * NC * D_STATE * D_INNER;

    unsigned short* xb     = (unsigned short*)(xpart + (size_t)XSK * M_ROWS * XPAD);
    unsigned short* yb     = xb + (size_t)M_ROWS * D_MODEL;
    unsigned short* xcb    = yb + (size_t)M_ROWS * D_INNER;
    unsigned short* xdbl_b = xcb + (size_t)M_ROWS * D_INNER;
    unsigned short* wb_in  = xdbl_b + (size_t)M_ROWS * XPAD;
    unsigned short* wb_out = wb_in + (size_t)NLAYERS * 2 * D_INNER * D_MODEL;
    unsigned short* wb_fc  = wb_out + (size_t)NLAYERS * D_MODEL * D_INNER;
    unsigned short* wb_x   = wb_fc + (size_t)VOCAB * D_MODEL;
    unsigned short* wb_dt  = wb_x + (size_t)NLAYERS * XPAD * D_INNER;

    // ---- weight casts ----
    {
        int n4 = NLAYERS * 2 * D_INNER * D_MODEL / 4;
        cast_kernel<<<(n4 + 255) / 256, 256, 0, stream>>>(in_proj, wb_in, n4);
        n4 = NLAYERS * D_MODEL * D_INNER / 4;
        cast_kernel<<<(n4 + 255) / 256, 256, 0, stream>>>(out_proj, wb_out, n4);
        n4 = VOCAB * D_MODEL / 4;
        cast_kernel<<<(n4 + 255) / 256, 256, 0, stream>>>(fc_w, wb_fc, n4);
        n4 = NLAYERS * D_INNER * DT_RANK / 4;
        cast_kernel<<<(n4 + 255) / 256, 256, 0, stream>>>(dt_w, wb_dt, n4);
        n4 = NLAYERS * XPAD * D_INNER / 4;
        cast_pad_xproj<<<(n4 + 255) / 256, 256, 0, stream>>>(x_proj, wb_x);
    }

    // ---- embedding (fp32 + bf16) ----
    gather_kernel<<<M_ROWS, 256, 0, stream>>>(ids, embed, x, xb);

    for (int i = 0; i < NLAYERS; ++i) {
        const unsigned short* W_in_b  = wb_in + (size_t)i * 2 * D_INNER * D_MODEL;
        const unsigned short* W_out_b = wb_out + (size_t)i * D_MODEL * D_INNER;
        const unsigned short* W_x_b   = wb_x + (size_t)i * XPAD * D_INNER;
        const unsigned short* W_dt_b  = wb_dt + (size_t)i * D_INNER * DT_RANK;
        const float* cw    = conv_w + (size_t)i * D_INNER * 4;
        const float* cb    = conv_b + (size_t)i * D_INNER;
        const float* b_dt  = dt_b + (size_t)i * D_INNER;
        const float* Al    = A_log + (size_t)i * D_INNER * D_STATE;
        const float* Dl    = Dp + (size_t)i * D_INNER;
        const float* g     = ln_g + (size_t)i * D_MODEL;
        const float* bb    = ln_b + (size_t)i * D_MODEL;

        // xz = x @ in_proj^T   (2048 x 4096, K=1024)   grid 16x32
        gemm_bf16_nt<0><<<dim3(M_ROWS / 128, 2 * D_INNER / 128), 256, 0, stream>>>(
            xb, D_MODEL, W_in_b, D_MODEL, xz, 2 * D_INNER, D_MODEL, nullptr);

        // xc = silu(conv(xz[:, :2048]) + cb)  (fp32 + bf16)
        conv_silu_kernel<<<(M_ROWS * D_INNER) / 256, 256, 0, stream>>>(xz, cw, cb, xc, xcb);

        // x_dbl partials: (2048 x 128, K=2048 split XSK x 256)  grid 16x1x8
        gemm_bf16_nt<0><<<dim3(M_ROWS / 128, 1, XSK), 256, 0, stream>>>(
            xcb, D_INNER, W_x_b, D_INNER, xpart, XPAD, D_INNER / XSK, nullptr);
        reduce_xdbl<<<(M_ROWS * XPAD / 4) / 256, 256, 0, stream>>>(xpart, xdbl, xdbl_b);

        // dt = softplus(x_dbl[:, :64] @ dt_w^T + b_dt)  (2048 x 2048, K=64)  grid 16x16
        gemm_bf16_nt<1><<<dim3(M_ROWS / 128, D_INNER / 128), 256, 0, stream>>>(
            xdbl_b, XPAD, W_dt_b, DT_RANK, dtbuf, D_INNER, DT_RANK, b_dt);

        // chunk-parallel scan -> yb (bf16)
        scan_partial<<<BATCH * NC * (D_INNER / 256), 256, 0, stream>>>(
            dtbuf, xdbl, xc, Al, Hbuf, Pbuf);
        scan_combine<<<(BATCH * D_STATE * D_INNER) / 256, 256, 0, stream>>>(Hbuf, Pbuf);
        scan_final<<<BATCH * NC * (D_INNER / 256), 256, 0, stream>>>(
            dtbuf, xdbl, xc, xz, Al, Dl, Pbuf, yb);

        // tmp = y @ out_proj^T   (2048 x 1024, K=2048)   grid 16x8
        gemm_bf16_nt<0><<<dim3(M_ROWS / 128, D_MODEL / 128), 256, 0, stream>>>(
            yb, D_INNER, W_out_b, D_INNER, tmp, D_MODEL, D_INNER, nullptr);

        // x = LN(tmp + x)  (fp32 + bf16)
        ln_kernel<true><<<M_ROWS, 256, 0, stream>>>(tmp, x, x, xb, g, bb);
    }

    // final LN -> tmp + xb
    ln_kernel<false><<<M_ROWS, 256, 0, stream>>>(nullptr, x, tmp, xb, fn_g, fn_b);

    // logits = xf @ fc_w^T + fc_b   (2048 x 32000, K=1024)   grid 16x250
    gemm_bf16_nt<2><<<dim3(M_ROWS / 128, VOCAB / 128), 256, 0, stream>>>(
        xb, D_MODEL, wb_fc, D_MODEL, logits, VOCAB, D_MODEL, fc_b);
}

// Round 7
// 1001.325 us; speedup vs baseline: 6.9068x; 1.0161x over previous
//
#include <hip/hip_runtime.h>
#include <cstddef>
#include <cstdint>

#define D_MODEL 1024
#define D_INNER 2048
#define DT_RANK 64
#define D_STATE 8
#define NLAYERS 4
#define BATCH 2
#define SEQ 1024
#define M_ROWS (BATCH*SEQ)   /* 2048 */
#define VOCAB 32000
#define XPAD 128             /* x_proj N padded 80 -> 128 */
#define NC 32                /* scan chunks */
#define LC 32                /* chunk length (NC*LC == SEQ) */
#define XSK 8                /* x_proj split-K factor */

typedef __attribute__((ext_vector_type(8))) short short8;
typedef __attribute__((ext_vector_type(4))) float f32x4;

#define GPTR(p) (const __attribute__((address_space(1))) void*)(p)
#define LPTR(p) (__attribute__((address_space(3))) void*)(p)

__device__ __forceinline__ float sigmoidf_(float x) { return 1.f / (1.f + __expf(-x)); }

__device__ __forceinline__ unsigned short f2bf(float f) {
    unsigned u = __float_as_uint(f);
    u += 0x7fffu + ((u >> 16) & 1u);         // round-to-nearest-even
    return (unsigned short)(u >> 16);
}

// ---------------------------------------------------------------------------
// fp32 -> bf16 cast (contiguous), 4 elems/thread.
// ---------------------------------------------------------------------------
__global__ __launch_bounds__(256) void cast_kernel(const float* __restrict__ in,
                                                   unsigned short* __restrict__ out, int n4)
{
    int i = blockIdx.x * 256 + threadIdx.x;
    if (i >= n4) return;
    float4 v = ((const float4*)in)[i];
    ushort4 o;
    o.x = f2bf(v.x); o.y = f2bf(v.y); o.z = f2bf(v.z); o.w = f2bf(v.w);
    ((ushort4*)out)[i] = o;
}

// ---------------------------------------------------------------------------
// x_proj weight: cast 4x(80,2048) fp32 -> 4x(128,2048) bf16, rows 80..127 = 0
// ---------------------------------------------------------------------------
__global__ __launch_bounds__(256) void cast_pad_xproj(const float* __restrict__ in,
                                                      unsigned short* __restrict__ out)
{
    int i = blockIdx.x * 256 + threadIdx.x;     // over 4*128*2048/4 = 262144
    if (i >= NLAYERS * XPAD * D_INNER / 4) return;
    int col4 = i & (D_INNER / 4 - 1);           // 512 col-groups
    int row = (i >> 9) & (XPAD - 1);
    int layer = i >> 16;
    ushort4 o = {0, 0, 0, 0};
    if (row < 80) {
        float4 v = ((const float4*)(in + ((size_t)layer * 80 + row) * D_INNER))[col4];
        o.x = f2bf(v.x); o.y = f2bf(v.y); o.z = f2bf(v.z); o.w = f2bf(v.w);
    }
    ((ushort4*)out)[i] = o;
}

// ---------------------------------------------------------------------------
// Embedding gather -> x (fp32) and xb (bf16)
// ---------------------------------------------------------------------------
__global__ __launch_bounds__(256) void gather_kernel(const int* __restrict__ ids,
                                                     const float* __restrict__ embed,
                                                     float* __restrict__ x,
                                                     unsigned short* __restrict__ xb)
{
    int m = blockIdx.x;
    int t = threadIdx.x;
    int id = ids[m];
    float4 v = ((const float4*)(embed + (size_t)id * D_MODEL))[t];
    ((float4*)(x + (size_t)m * D_MODEL))[t] = v;
    ushort4 o;
    o.x = f2bf(v.x); o.y = f2bf(v.y); o.z = f2bf(v.z); o.w = f2bf(v.w);
    ((ushort4*)(xb + (size_t)m * D_MODEL))[t] = o;
}

// ---------------------------------------------------------------------------
// bf16 MFMA GEMM  C[M,N] = A[M,K] * B[N,K]^T  (fp32 out)
// 128x128 tile, BK=32, 4 waves. Double-buffered LDS, counted-vmcnt pipeline:
// STAGE(next) -> s_waitcnt vmcnt(4) (cur landed, next in flight) -> s_barrier
// -> ds_read+MFMA -> s_barrier. Never drains vmcnt to 0 inside the loop (T4).
// T2 swizzle: 16B unit p = u ^ ((row>>1)&3); linear gload dest + inverse-
// swizzled global source (rule #21). Safety: per-wave vmcnt precedes bar1 so
// async LDS writes are published; bar2 orders reads before next overwrite.
// EPI: 0 none | 1 +bias,softplus | 2 +bias
// ---------------------------------------------------------------------------
template<int EPI>
__global__ __launch_bounds__(256) void gemm_bf16_nt(const unsigned short* __restrict__ A, int lda,
                                                    const unsigned short* __restrict__ B, int ldb,
                                                    float* __restrict__ C, int ldc,
                                                    int K, const float* __restrict__ bias)
{
    __shared__ unsigned short As[2][128 * 32];
    __shared__ unsigned short Bs[2][128 * 32];
    const int tid = threadIdx.x;

    const int gm = gridDim.x;
    const int bid = blockIdx.y * gm + blockIdx.x;
    const int q = (gm * gridDim.y) >> 3;           // nwg % 8 == 0 guaranteed
    const int swz = (bid & 7) * q + (bid >> 3);
    const int bm = (swz % gm) * 128, bn = (swz / gm) * 128;

    const int wid = tid >> 6, lane = tid & 63;
    const int wm = (wid >> 1) * 64, wn = (wid & 1) * 64;
    const int lrow = lane & 15, lkg = lane >> 4;

    const int srow = tid >> 2;                               // 0..63
    const int ksrc = ((tid & 3) ^ ((srow >> 1) & 3)) * 8;    // elems, const/thread
    const size_t kz = (size_t)blockIdx.z * K;
    const unsigned short* Ag = A + (size_t)(bm + srow) * lda + kz + ksrc;
    const unsigned short* Bg = B + (size_t)(bn + srow) * ldb + kz + ksrc;
    const size_t r64a = (size_t)64 * lda;
    const size_t r64b = (size_t)64 * ldb;

#define STAGE(buf, koff)                                                                              \
    do {                                                                                              \
        __builtin_amdgcn_global_load_lds(GPTR(Ag + (koff)),        LPTR(&As[buf][tid * 8]), 16, 0, 0);\
        __builtin_amdgcn_global_load_lds(GPTR(Ag + r64a + (koff)), LPTR(&As[buf][2048 + tid * 8]), 16, 0, 0);\
        __builtin_amdgcn_global_load_lds(GPTR(Bg + (koff)),        LPTR(&Bs[buf][tid * 8]), 16, 0, 0);\
        __builtin_amdgcn_global_load_lds(GPTR(Bg + r64b + (koff)), LPTR(&Bs[buf][2048 + tid * 8]), 16, 0, 0);\
    } while (0)

    f32x4 acc[4][4];
    #pragma unroll
    for (int i = 0; i < 4; ++i)
        #pragma unroll
        for (int j = 0; j < 4; ++j)
            acc[i][j] = f32x4{0.f, 0.f, 0.f, 0.f};

    STAGE(0, 0);                      // prologue

    int cur = 0;
    for (int k0 = 0; k0 < K; k0 += 32) {
        if (k0 + 32 < K) {
            STAGE(cur ^ 1, k0 + 32);                             // next tile in flight
            asm volatile("s_waitcnt vmcnt(4)" ::: "memory");     // cur's 4 landed
        } else {
            asm volatile("s_waitcnt vmcnt(0)" ::: "memory");     // final drain
        }
        __builtin_amdgcn_s_barrier();          // publish cur to all waves
        __builtin_amdgcn_sched_barrier(0);     // pin: no hoisting above the wait

        short8 af[4], bf[4];
        #pragma unroll
        for (int i = 0; i < 4; ++i) {
            int ra = wm + 16 * i + lrow;
            int pa = lkg ^ ((ra >> 1) & 3);
            af[i] = *(const short8*)(&As[cur][ra * 32 + pa * 8]);
            int rb = wn + 16 * i + lrow;
            int pb = lkg ^ ((rb >> 1) & 3);
            bf[i] = *(const short8*)(&Bs[cur][rb * 32 + pb * 8]);
        }
        #pragma unroll
        for (int i = 0; i < 4; ++i)
            #pragma unroll
            for (int j = 0; j < 4; ++j)
                acc[i][j] = __builtin_amdgcn_mfma_f32_16x16x32_bf16(af[i], bf[j], acc[i][j], 0, 0, 0);

        __builtin_amdgcn_s_barrier();          // all reads of cur done before overwrite
        cur ^= 1;
    }
#undef STAGE

    if (gridDim.z > 1) C += (size_t)blockIdx.z * M_ROWS * ldc;

    const int crow = bm + wm + lkg * 4;
    const int ccol = bn + wn + lrow;
    #pragma unroll
    for (int i = 0; i < 4; ++i) {
        #pragma unroll
        for (int j = 0; j < 4; ++j) {
            float bv = (EPI == 1 || EPI == 2) ? bias[ccol + 16 * j] : 0.f;
            float* Cp = C + (size_t)(crow + 16 * i) * ldc + ccol + 16 * j;
            #pragma unroll
            for (int r = 0; r < 4; ++r) {
                float v = acc[i][j][r] + bv;
                if (EPI == 1) v = (v > 20.f) ? v : log1pf(__expf(v));
                Cp[(size_t)r * ldc] = v;
            }
        }
    }
}

// ---------------------------------------------------------------------------
// 256x256-tile variant for the vocab GEMM: 512 thr = 8 waves (2M x 4N),
// BK=32, 64 KiB double-buffered LDS, same counted-vmcnt schedule & swizzle.
// Per-wave output 128x64 (8x4 fragments). 2x MFMA per staged KB vs 128².
// ---------------------------------------------------------------------------
template<int EPI>
__global__ __launch_bounds__(512) void gemm_bf16_nt256(const unsigned short* __restrict__ A, int lda,
                                                       const unsigned short* __restrict__ B, int ldb,
                                                       float* __restrict__ C, int ldc,
                                                       int K, const float* __restrict__ bias)
{
    __shared__ unsigned short As[2][256 * 32];
    __shared__ unsigned short Bs[2][256 * 32];
    const int tid = threadIdx.x;

    const int gm = gridDim.x;
    const int bid = blockIdx.y * gm + blockIdx.x;
    const int q = (gm * gridDim.y) >> 3;
    const int swz = (bid & 7) * q + (bid >> 3);
    const int bm = (swz % gm) * 256, bn = (swz / gm) * 256;

    const int wid = tid >> 6, lane = tid & 63;
    const int wm = (wid >> 2) * 128, wn = (wid & 3) * 64;
    const int lrow = lane & 15, lkg = lane >> 4;

    // staging: 512 thr x 8 elems = 128 rows/call; 2 calls each for A and B.
    const int srow = tid >> 2;                               // 0..127
    const int ksrc = ((tid & 3) ^ ((srow >> 1) & 3)) * 8;
    const unsigned short* Ag = A + (size_t)(bm + srow) * lda + ksrc;
    const unsigned short* Bg = B + (size_t)(bn + srow) * ldb + ksrc;
    const size_t r128a = (size_t)128 * lda;
    const size_t r128b = (size_t)128 * ldb;

#define STAGE2(buf, koff)                                                                               \
    do {                                                                                                \
        __builtin_amdgcn_global_load_lds(GPTR(Ag + (koff)),         LPTR(&As[buf][tid * 8]), 16, 0, 0); \
        __builtin_amdgcn_global_load_lds(GPTR(Ag + r128a + (koff)), LPTR(&As[buf][4096 + tid * 8]), 16, 0, 0);\
        __builtin_amdgcn_global_load_lds(GPTR(Bg + (koff)),         LPTR(&Bs[buf][tid * 8]), 16, 0, 0); \
        __builtin_amdgcn_global_load_lds(GPTR(Bg + r128b + (koff)), LPTR(&Bs[buf][4096 + tid * 8]), 16, 0, 0);\
    } while (0)

    f32x4 acc[8][4];
    #pragma unroll
    for (int i = 0; i < 8; ++i)
        #pragma unroll
        for (int j = 0; j < 4; ++j)
            acc[i][j] = f32x4{0.f, 0.f, 0.f, 0.f};

    STAGE2(0, 0);

    int cur = 0;
    for (int k0 = 0; k0 < K; k0 += 32) {
        if (k0 + 32 < K) {
            STAGE2(cur ^ 1, k0 + 32);
            asm volatile("s_waitcnt vmcnt(4)" ::: "memory");
        } else {
            asm volatile("s_waitcnt vmcnt(0)" ::: "memory");
        }
        __builtin_amdgcn_s_barrier();
        __builtin_amdgcn_sched_barrier(0);

        short8 af[8], bf[4];
        #pragma unroll
        for (int j = 0; j < 4; ++j) {
            int rb = wn + 16 * j + lrow;
            int pb = lkg ^ ((rb >> 1) & 3);
            bf[j] = *(const short8*)(&Bs[cur][rb * 32 + pb * 8]);
        }
        #pragma unroll
        for (int i = 0; i < 8; ++i) {
            int ra = wm + 16 * i + lrow;
            int pa = lkg ^ ((ra >> 1) & 3);
            af[i] = *(const short8*)(&As[cur][ra * 32 + pa * 8]);
        }
        #pragma unroll
        for (int i = 0; i < 8; ++i)
            #pragma unroll
            for (int j = 0; j < 4; ++j)
                acc[i][j] = __builtin_amdgcn_mfma_f32_16x16x32_bf16(af[i], bf[j], acc[i][j], 0, 0, 0);

        __builtin_amdgcn_s_barrier();
        cur ^= 1;
    }
#undef STAGE2

    const int crow = bm + wm + lkg * 4;
    const int ccol = bn + wn + lrow;
    #pragma unroll
    for (int i = 0; i < 8; ++i) {
        #pragma unroll
        for (int j = 0; j < 4; ++j) {
            float bv = (EPI == 2) ? bias[ccol + 16 * j] : 0.f;
            float* Cp = C + (size_t)(crow + 16 * i) * ldc + ccol + 16 * j;
            #pragma unroll
            for (int r = 0; r < 4; ++r)
                Cp[(size_t)r * ldc] = acc[i][j][r] + bv;
        }
    }
}

// ---------------------------------------------------------------------------
// Reduce XSK split-K partials -> xdbl (fp32) + xdbl_b (bf16)
// ---------------------------------------------------------------------------
__global__ __launch_bounds__(256) void reduce_xdbl(const float* __restrict__ part,
                                                   float* __restrict__ xdbl,
                                                   unsigned short* __restrict__ xdbl_b)
{
    int i = blockIdx.x * 256 + threadIdx.x;     // over 2048*128/4 = 65536
    float4 s = ((const float4*)part)[i];
    #pragma unroll
    for (int z = 1; z < XSK; ++z) {
        float4 v = ((const float4*)part)[(size_t)z * (M_ROWS * XPAD / 4) + i];
        s.x += v.x; s.y += v.y; s.z += v.z; s.w += v.w;
    }
    ((float4*)xdbl)[i] = s;
    ushort4 o;
    o.x = f2bf(s.x); o.y = f2bf(s.y); o.z = f2bf(s.z); o.w = f2bf(s.w);
    ((ushort4*)xdbl_b)[i] = o;
}

// ---------------------------------------------------------------------------
// Causal depthwise conv1d (k=4) + bias + SiLU -> xc (fp32) and xcb (bf16)
// ---------------------------------------------------------------------------
__global__ __launch_bounds__(256) void conv_silu_kernel(const float* __restrict__ xz,
                                                        const float* __restrict__ cw,
                                                        const float* __restrict__ cb,
                                                        float* __restrict__ xc,
                                                        unsigned short* __restrict__ xcb)
{
    int idx = blockIdx.x * 256 + threadIdx.x;
    int d = idx & (D_INNER - 1);
    int m = idx >> 11;
    int l = m & (SEQ - 1);
    int b = m >> 10;
    float w0 = cw[d * 4 + 0], w1 = cw[d * 4 + 1], w2 = cw[d * 4 + 2], w3 = cw[d * 4 + 3];
    float s = cb[d];
    const float* base = xz + ((size_t)b * SEQ) * (2 * D_INNER) + d;
    if (l - 3 >= 0) s += base[(size_t)(l - 3) * (2 * D_INNER)] * w0;
    if (l - 2 >= 0) s += base[(size_t)(l - 2) * (2 * D_INNER)] * w1;
    if (l - 1 >= 0) s += base[(size_t)(l - 1) * (2 * D_INNER)] * w2;
    s += base[(size_t)l * (2 * D_INNER)] * w3;
    float v = s * sigmoidf_(s);
    xc[(size_t)m * D_INNER + d] = v;
    xcb[(size_t)m * D_INNER + d] = f2bf(v);
}

// ---------------------------------------------------------------------------
// Chunk-parallel selective scan (linear recurrence decomposition).
// ---------------------------------------------------------------------------
__global__ __launch_bounds__(256) void scan_partial(const float* __restrict__ dt,
                                                    const float* __restrict__ xdbl,
                                                    const float* __restrict__ xc,
                                                    const float* __restrict__ A_log,
                                                    float* __restrict__ H,
                                                    float* __restrict__ P)
{
    const int tid = threadIdx.x;
    const int b = blockIdx.x & 1;
    const int c = (blockIdx.x >> 1) & (NC - 1);
    const int d = ((blockIdx.x >> 6) << 8) + tid;

    __shared__ float Bs[LC][8];
    {
        int r = tid >> 3, n = tid & 7;
        Bs[r][n] = xdbl[(size_t)(b * SEQ + c * LC + r) * XPAD + DT_RANK + n];
    }
    __syncthreads();

    float An[8];
    #pragma unroll
    for (int n = 0; n < 8; ++n) An[n] = -__expf(A_log[d * 8 + n]);
    float h[8] = {0.f,0.f,0.f,0.f,0.f,0.f,0.f,0.f};
    float p[8] = {1.f,1.f,1.f,1.f,1.f,1.f,1.f,1.f};

    const float* dtp = dt + (size_t)(b * SEQ + c * LC) * D_INNER + d;
    const float* xcp = xc + (size_t)(b * SEQ + c * LC) * D_INNER + d;
    for (int l = 0; l < LC; ++l) {
        float dtv = dtp[(size_t)l * D_INNER];
        float ux  = dtv * xcp[(size_t)l * D_INNER];
        #pragma unroll
        for (int n = 0; n < 8; ++n) {
            float dA = __expf(dtv * An[n]);
            h[n] = dA * h[n] + Bs[l][n] * ux;
            p[n] *= dA;
        }
    }
    size_t base = (size_t)((b * NC + c) * 8) * D_INNER + d;
    #pragma unroll
    for (int n = 0; n < 8; ++n) {
        H[base + (size_t)n * D_INNER] = h[n];
        P[base + (size_t)n * D_INNER] = p[n];
    }
}

__global__ __launch_bounds__(256) void scan_combine(const float* __restrict__ H,
                                                    float* __restrict__ P /* -> h0 */)
{
    int idx = blockIdx.x * 256 + threadIdx.x;   // 32768 = 2*8*2048
    int d = idx & (D_INNER - 1);
    int n = (idx >> 11) & 7;
    int b = idx >> 14;
    float hp = 0.f;
    for (int c = 0; c < NC; ++c) {
        size_t base = (size_t)((b * NC + c) * 8 + n) * D_INNER + d;
        float Pv = P[base], Hv = H[base];
        P[base] = hp;
        hp = Pv * hp + Hv;
    }
}

__global__ __launch_bounds__(256) void scan_final(const float* __restrict__ dt,
                                                  const float* __restrict__ xdbl,
                                                  const float* __restrict__ xc,
                                                  const float* __restrict__ xz,
                                                  const float* __restrict__ A_log,
                                                  const float* __restrict__ Dp,
                                                  const float* __restrict__ h0,
                                                  unsigned short* __restrict__ yb)
{
    const int tid = threadIdx.x;
    const int b = blockIdx.x & 1;
    const int c = (blockIdx.x >> 1) & (NC - 1);
    const int d = ((blockIdx.x >> 6) << 8) + tid;

    __shared__ float Bs[LC][8];
    __shared__ float Cs[LC][8];
    {
        int r = tid >> 3, n = tid & 7;
        size_t xrow = (size_t)(b * SEQ + c * LC + r) * XPAD;
        Bs[r][n] = xdbl[xrow + DT_RANK + n];
        Cs[r][n] = xdbl[xrow + DT_RANK + 8 + n];
    }
    __syncthreads();

    float An[8], h[8];
    size_t base = (size_t)((b * NC + c) * 8) * D_INNER + d;
    #pragma unroll
    for (int n = 0; n < 8; ++n) {
        An[n] = -__expf(A_log[d * 8 + n]);
        h[n] = h0[base + (size_t)n * D_INNER];
    }
    const float Dv = Dp[d];

    const float* dtp = dt + (size_t)(b * SEQ + c * LC) * D_INNER + d;
    const float* xcp = xc + (size_t)(b * SEQ + c * LC) * D_INNER + d;
    const float* zp  = xz + (size_t)(b * SEQ + c * LC) * (2 * D_INNER) + D_INNER + d;
    unsigned short* ybp = yb + (size_t)(b * SEQ + c * LC) * D_INNER + d;

    for (int l = 0; l < LC; ++l) {
        float dtv = dtp[(size_t)l * D_INNER];
        float xcv = xcp[(size_t)l * D_INNER];
        float zv  = zp[(size_t)l * (2 * D_INNER)];
        float ux = dtv * xcv;
        float acc = 0.f;
        #pragma unroll
        for (int n = 0; n < 8; ++n) {
            float dA = __expf(dtv * An[n]);
            h[n] = dA * h[n] + Bs[l][n] * ux;
            acc += h[n] * Cs[l][n];
        }
        float yv = (acc + xcv * Dv) * (zv * sigmoidf_(zv));
        ybp[(size_t)l * D_INNER] = f2bf(yv);
    }
}

// ---------------------------------------------------------------------------
// LayerNorm (1024). ADD: out = LN(extra + xin) else LN(xin). Emits fp32 + bf16.
// ---------------------------------------------------------------------------
template<bool ADD>
__global__ __launch_bounds__(256) void ln_kernel(const float* __restrict__ extra,
                                                 const float* __restrict__ xin,
                                                 float* __restrict__ xout,
                                                 unsigned short* __restrict__ xbout,
                                                 const float* __restrict__ g,
                                                 const float* __restrict__ bb)
{
    int m = blockIdx.x;
    int t = threadIdx.x;
    float4 v = ((const float4*)(xin + (size_t)m * D_MODEL))[t];
    if (ADD) {
        float4 e = ((const float4*)(extra + (size_t)m * D_MODEL))[t];
        v.x += e.x; v.y += e.y; v.z += e.z; v.w += e.w;
    }
    float s  = v.x + v.y + v.z + v.w;
    float s2 = v.x * v.x + v.y * v.y + v.z * v.z + v.w * v.w;
    for (int off = 32; off; off >>= 1) {
        s  += __shfl_down(s, off);
        s2 += __shfl_down(s2, off);
    }
    __shared__ float red[8];
    int wid = t >> 6, lane = t & 63;
    if (lane == 0) { red[wid] = s; red[wid + 4] = s2; }
    __syncthreads();
    if (t == 0) {
        float a  = red[0] + red[1] + red[2] + red[3];
        float b2 = red[4] + red[5] + red[6] + red[7];
        float mu = a * (1.f / D_MODEL);
        red[0] = mu;
        red[4] = b2 * (1.f / D_MODEL) - mu * mu;
    }
    __syncthreads();
    float mu = red[0];
    float rs = rsqrtf(red[4] + 1e-5f);
    float4 gg = ((const float4*)g)[t];
    float4 bv = ((const float4*)bb)[t];
    float4 o;
    o.x = (v.x - mu) * rs * gg.x + bv.x;
    o.y = (v.y - mu) * rs * gg.y + bv.y;
    o.z = (v.z - mu) * rs * gg.z + bv.z;
    o.w = (v.w - mu) * rs * gg.w + bv.w;
    ((float4*)(xout + (size_t)m * D_MODEL))[t] = o;
    ushort4 ob;
    ob.x = f2bf(o.x); ob.y = f2bf(o.y); ob.z = f2bf(o.z); ob.w = f2bf(o.w);
    ((ushort4*)(xbout + (size_t)m * D_MODEL))[t] = ob;
}

// ---------------------------------------------------------------------------
extern "C" void kernel_launch(void* const* d_in, const int* in_sizes, int n_in,
                              void* d_out, int out_size, void* d_ws, size_t ws_size,
                              hipStream_t stream)
{
    const int*   ids      = (const int*)d_in[0];
    const float* embed    = (const float*)d_in[1];
    const float* in_proj  = (const float*)d_in[2];
    const float* conv_w   = (const float*)d_in[3];
    const float* conv_b   = (const float*)d_in[4];
    const float* x_proj   = (const float*)d_in[5];
    const float* dt_w     = (const float*)d_in[6];
    const float* dt_b     = (const float*)d_in[7];
    const float* A_log    = (const float*)d_in[8];
    const float* Dp       = (const float*)d_in[9];
    const float* out_proj = (const float*)d_in[10];
    const float* ln_g     = (const float*)d_in[11];
    const float* ln_b     = (const float*)d_in[12];
    const float* fn_g     = (const float*)d_in[13];
    const float* fn_b     = (const float*)d_in[14];
    const float* fc_w     = (const float*)d_in[15];
    const float* fc_b     = (const float*)d_in[16];
    float* logits = (float*)d_out;

    // ---- workspace layout ----
    float* ws = (float*)d_ws;
    float* x     = ws;                                   // 2048*1024
    float* xz    = x + (size_t)M_ROWS * D_MODEL;         // 2048*4096
    float* xc    = xz + (size_t)M_ROWS * 2 * D_INNER;    // 2048*2048
    float* xdbl  = xc + (size_t)M_ROWS * D_INNER;        // 2048*128
    float* dtbuf = xdbl + (size_t)M_ROWS * XPAD;         // 2048*2048
    float* tmp   = dtbuf + (size_t)M_ROWS * D_INNER;     // 2048*1024
    float* xpart = tmp + (size_t)M_ROWS * D_MODEL;       // XSK*2048*128

    float* Hbuf = tmp;
    float* Pbuf = tmp + (size_t)BATCH * NC * D_STATE * D_INNER;

    unsigned short* xb     = (unsigned short*)(xpart + (size_t)XSK * M_ROWS * XPAD);
    unsigned short* yb     = xb + (size_t)M_ROWS * D_MODEL;
    unsigned short* xcb    = yb + (size_t)M_ROWS * D_INNER;
    unsigned short* xdbl_b = xcb + (size_t)M_ROWS * D_INNER;
    unsigned short* wb_in  = xdbl_b + (size_t)M_ROWS * XPAD;
    unsigned short* wb_out = wb_in + (size_t)NLAYERS * 2 * D_INNER * D_MODEL;
    unsigned short* wb_fc  = wb_out + (size_t)NLAYERS * D_MODEL * D_INNER;
    unsigned short* wb_x   = wb_fc + (size_t)VOCAB * D_MODEL;
    unsigned short* wb_dt  = wb_x + (size_t)NLAYERS * XPAD * D_INNER;

    // ---- weight casts ----
    {
        int n4 = NLAYERS * 2 * D_INNER * D_MODEL / 4;
        cast_kernel<<<(n4 + 255) / 256, 256, 0, stream>>>(in_proj, wb_in, n4);
        n4 = NLAYERS * D_MODEL * D_INNER / 4;
        cast_kernel<<<(n4 + 255) / 256, 256, 0, stream>>>(out_proj, wb_out, n4);
        n4 = VOCAB * D_MODEL / 4;
        cast_kernel<<<(n4 + 255) / 256, 256, 0, stream>>>(fc_w, wb_fc, n4);
        n4 = NLAYERS * D_INNER * DT_RANK / 4;
        cast_kernel<<<(n4 + 255) / 256, 256, 0, stream>>>(dt_w, wb_dt, n4);
        n4 = NLAYERS * XPAD * D_INNER / 4;
        cast_pad_xproj<<<(n4 + 255) / 256, 256, 0, stream>>>(x_proj, wb_x);
    }

    // ---- embedding (fp32 + bf16) ----
    gather_kernel<<<M_ROWS, 256, 0, stream>>>(ids, embed, x, xb);

    for (int i = 0; i < NLAYERS; ++i) {
        const unsigned short* W_in_b  = wb_in + (size_t)i * 2 * D_INNER * D_MODEL;
        const unsigned short* W_out_b = wb_out + (size_t)i * D_MODEL * D_INNER;
        const unsigned short* W_x_b   = wb_x + (size_t)i * XPAD * D_INNER;
        const unsigned short* W_dt_b  = wb_dt + (size_t)i * D_INNER * DT_RANK;
        const float* cw    = conv_w + (size_t)i * D_INNER * 4;
        const float* cb    = conv_b + (size_t)i * D_INNER;
        const float* b_dt  = dt_b + (size_t)i * D_INNER;
        const float* Al    = A_log + (size_t)i * D_INNER * D_STATE;
        const float* Dl    = Dp + (size_t)i * D_INNER;
        const float* g     = ln_g + (size_t)i * D_MODEL;
        const float* bb    = ln_b + (size_t)i * D_MODEL;

        // xz = x @ in_proj^T   (2048 x 4096, K=1024)   grid 16x32
        gemm_bf16_nt<0><<<dim3(M_ROWS / 128, 2 * D_INNER / 128), 256, 0, stream>>>(
            xb, D_MODEL, W_in_b, D_MODEL, xz, 2 * D_INNER, D_MODEL, nullptr);

        // xc = silu(conv(xz[:, :2048]) + cb)  (fp32 + bf16)
        conv_silu_kernel<<<(M_ROWS * D_INNER) / 256, 256, 0, stream>>>(xz, cw, cb, xc, xcb);

        // x_dbl partials: (2048 x 128, K=2048 split XSK x 256)  grid 16x1x8
        gemm_bf16_nt<0><<<dim3(M_ROWS / 128, 1, XSK), 256, 0, stream>>>(
            xcb, D_INNER, W_x_b, D_INNER, xpart, XPAD, D_INNER / XSK, nullptr);
        reduce_xdbl<<<(M_ROWS * XPAD / 4) / 256, 256, 0, stream>>>(xpart, xdbl, xdbl_b);

        // dt = softplus(x_dbl[:, :64] @ dt_w^T + b_dt)  (2048 x 2048, K=64)  grid 16x16
        gemm_bf16_nt<1><<<dim3(M_ROWS / 128, D_INNER / 128), 256, 0, stream>>>(
            xdbl_b, XPAD, W_dt_b, DT_RANK, dtbuf, D_INNER, DT_RANK, b_dt);

        // chunk-parallel scan -> yb (bf16)
        scan_partial<<<BATCH * NC * (D_INNER / 256), 256, 0, stream>>>(
            dtbuf, xdbl, xc, Al, Hbuf, Pbuf);
        scan_combine<<<(BATCH * D_STATE * D_INNER) / 256, 256, 0, stream>>>(Hbuf, Pbuf);
        scan_final<<<BATCH * NC * (D_INNER / 256), 256, 0, stream>>>(
            dtbuf, xdbl, xc, xz, Al, Dl, Pbuf, yb);

        // tmp = y @ out_proj^T   (2048 x 1024, K=2048)   grid 16x8
        gemm_bf16_nt<0><<<dim3(M_ROWS / 128, D_MODEL / 128), 256, 0, stream>>>(
            yb, D_INNER, W_out_b, D_INNER, tmp, D_MODEL, D_INNER, nullptr);

        // x = LN(tmp + x)  (fp32 + bf16)
        ln_kernel<true><<<M_ROWS, 256, 0, stream>>>(tmp, x, x, xb, g, bb);
    }

    // final LN -> tmp + xb
    ln_kernel<false><<<M_ROWS, 256, 0, stream>>>(nullptr, x, tmp, xb, fn_g, fn_b);

    // logits = xf @ fc_w^T + fc_b   (2048 x 32000, K=1024)   grid 8x125, 512 thr
    gemm_bf16_nt256<2><<<dim3(M_ROWS / 256, VOCAB / 256), 512, 0, stream>>>(
        xb, D_MODEL, wb_fc, D_MODEL, logits, VOCAB, D_MODEL, fc_b);
}